// Round 1
// baseline (4372.900 us; speedup 1.0000x reference)
//
#include <hip/hip_runtime.h>
#include <hip/hip_bf16.h>

#define D_MODEL 1024
#define N_HEADS 16
#define D_HEAD  64
#define D_FF    2048
#define BATCH   4
#define SEQ     1024
#define ROWS    (BATCH*SEQ)   // 4096

typedef __bf16  bf16x8 __attribute__((ext_vector_type(8)));
typedef float   f32x4  __attribute__((ext_vector_type(4)));
typedef unsigned int u32x4 __attribute__((ext_vector_type(4)));
typedef unsigned short u16;

// ---------------- prep: f32 -> bf16 cast ----------------
__global__ __launch_bounds__(256)
void cast_bf16_kernel(const float* __restrict__ src, __hip_bfloat16* __restrict__ dst, int n){
  int i = (blockIdx.x*blockDim.x + threadIdx.x)*4;
  if (i + 3 < n){
    float4 v = *(const float4*)(src + i);
    dst[i+0] = __float2bfloat16(v.x);
    dst[i+1] = __float2bfloat16(v.y);
    dst[i+2] = __float2bfloat16(v.z);
    dst[i+3] = __float2bfloat16(v.w);
  }
}

// ---------------- prep: transpose + cast (W[R][C] -> WT[C][R] bf16) ----------------
__global__ __launch_bounds__(256)
void transpose_cast_kernel(const float* __restrict__ src, __hip_bfloat16* __restrict__ dst,
                           int R, int C){
  __shared__ float tile[32][33];
  int c0 = blockIdx.x*32, r0 = blockIdx.y*32;
  int tx = threadIdx.x & 31, ty = threadIdx.x >> 5;  // ty in 0..7
  #pragma unroll
  for (int i=0;i<32;i+=8)
    tile[ty+i][tx] = src[(size_t)(r0+ty+i)*C + (c0+tx)];
  __syncthreads();
  #pragma unroll
  for (int i=0;i<32;i+=8)
    dst[(size_t)(c0+ty+i)*R + (r0+tx)] = __float2bfloat16(tile[tx][ty+i]);
}

// ---------------- bf16 MFMA GEMM: C[M][N] = A[M][K] @ B[K][N], B given transposed BT[N][K]
// 128x128 tile, BK=32, 4 waves (2x2), each wave 64x64 via 4x4 16x16x32 MFMAs.
template<int OUT_BF16>
__global__ __launch_bounds__(256, 2)
void gemm_bt_kernel(const u16* __restrict__ A, const u16* __restrict__ BT,
                    const float* __restrict__ bias, void* __restrict__ Cout,
                    int M, int N, int K){
  __shared__ u16 As[128][40];   // +8 pad keeps 16B alignment, 2-way-max bank aliasing
  __shared__ u16 Bs[128][40];
  const int m0 = blockIdx.y*128, n0 = blockIdx.x*128;
  const int t = threadIdx.x;
  const int wid = t>>6, lane = t&63;
  const int wm = wid>>1, wn = wid&1;
  const int lr = lane&15, lk = (lane>>4)*8;

  f32x4 acc[4][4] = {};

  for (int kt=0; kt<K; kt+=32){
    __syncthreads();
    #pragma unroll
    for (int it=0; it<2; ++it){
      int idx = it*256 + t;
      int row = idx>>2, seg = idx&3;
      u32x4 va = *(const u32x4*)(A  + (size_t)(m0+row)*K + kt + seg*8);
      *(u32x4*)&As[row][seg*8] = va;
      u32x4 vb = *(const u32x4*)(BT + (size_t)(n0+row)*K + kt + seg*8);
      *(u32x4*)&Bs[row][seg*8] = vb;
    }
    __syncthreads();
    bf16x8 af[4], bfr[4];
    #pragma unroll
    for (int f=0; f<4; ++f){
      af[f]  = *(const bf16x8*)&As[wm*64 + f*16 + lr][lk];
      bfr[f] = *(const bf16x8*)&Bs[wn*64 + f*16 + lr][lk];
    }
    #pragma unroll
    for (int i=0;i<4;++i)
      #pragma unroll
      for (int j=0;j<4;++j)
        acc[i][j] = __builtin_amdgcn_mfma_f32_16x16x32_bf16(af[i], bfr[j], acc[i][j], 0,0,0);
  }

  const int r_in = (lane>>4)*4;
  #pragma unroll
  for (int i=0;i<4;++i){
    #pragma unroll
    for (int j=0;j<4;++j){
      int col = n0 + wn*64 + j*16 + lr;
      float bv = bias ? bias[col] : 0.f;
      #pragma unroll
      for (int e=0;e<4;++e){
        int row = m0 + wm*64 + i*16 + r_in + e;
        float v = acc[i][j][e] + bv;
        if (OUT_BF16) ((__hip_bfloat16*)Cout)[(size_t)row*N + col] = __float2bfloat16(v);
        else          ((float*)Cout)[(size_t)row*N + col] = v;
      }
    }
  }
}

// ---------------- attention: one wave per 4 query rows, lane = head-dim ----------------
__global__ __launch_bounds__(64)
void attn_kernel(const float* __restrict__ qp, const float* __restrict__ kp,
                 const float* __restrict__ vp, const int* __restrict__ mask,
                 __hip_bfloat16* __restrict__ out){
  const int TQ = 4;
  int lane = threadIdx.x;
  int tile = blockIdx.x;
  int qtiles = SEQ/TQ;
  int q0 = (tile % qtiles)*TQ;
  int bh = tile / qtiles;
  int h = bh % N_HEADS, b = bh / N_HEADS;
  size_t base = (size_t)b*SEQ*D_MODEL + h*D_HEAD + lane;
  const float scale = 0.03125f;  // 1/sqrt(D_MODEL)

  float q[TQ], m[TQ], l[TQ], o[TQ];
  #pragma unroll
  for (int j=0;j<TQ;++j){
    q[j] = qp[base + (size_t)(q0+j)*D_MODEL]*scale;
    m[j] = -1e30f; l[j] = 0.f; o[j] = 0.f;
  }
  const int* mrow = mask + b*SEQ;
  for (int k=0;k<SEQ;++k){
    float kv = kp[base + (size_t)k*D_MODEL];
    float vv = vp[base + (size_t)k*D_MODEL];
    bool valid = (mrow[k] != 0);
    #pragma unroll
    for (int j=0;j<TQ;++j){
      float s = q[j]*kv;
      #pragma unroll
      for (int off=32; off; off>>=1) s += __shfl_xor(s, off);
      s = valid ? s : -1e30f;
      float mn = fmaxf(m[j], s);
      float c  = __expf(m[j]-mn);
      float p  = __expf(s-mn);
      l[j] = l[j]*c + p;
      o[j] = o[j]*c + p*vv;
      m[j] = mn;
    }
  }
  #pragma unroll
  for (int j=0;j<TQ;++j)
    out[base + (size_t)(q0+j)*D_MODEL] = __float2bfloat16(o[j]/l[j]);
}

// ---------------- fused: t = relu(a)+res; layernorm(t)*g+b -> outf (+ optional bf16) ----------------
__global__ __launch_bounds__(256)
void ln_fused_kernel(const float* __restrict__ a, const float* __restrict__ res,
                     const float* __restrict__ g, const float* __restrict__ be,
                     float* __restrict__ outf, __hip_bfloat16* __restrict__ outb){
  int row = blockIdx.x, t = threadIdx.x;
  size_t rb = (size_t)row*D_MODEL;
  float4 av = *(const float4*)(a  + rb + t*4);
  float4 rv = *(const float4*)(res+ rb + t*4);
  float v0 = fmaxf(av.x,0.f)+rv.x;
  float v1 = fmaxf(av.y,0.f)+rv.y;
  float v2 = fmaxf(av.z,0.f)+rv.z;
  float v3 = fmaxf(av.w,0.f)+rv.w;
  float sum = v0+v1+v2+v3;
  float ss  = v0*v0+v1*v1+v2*v2+v3*v3;
  #pragma unroll
  for (int off=32; off; off>>=1){ sum += __shfl_xor(sum,off); ss += __shfl_xor(ss,off); }
  __shared__ float red[8];
  int wid = t>>6, lane = t&63;
  if (lane==0){ red[wid]=sum; red[4+wid]=ss; }
  __syncthreads();
  sum = red[0]+red[1]+red[2]+red[3];
  ss  = red[4]+red[5]+red[6]+red[7];
  float mu  = sum*(1.f/1024.f);
  float var = ss*(1.f/1024.f) - mu*mu;
  float rstd = rsqrtf(var + 1e-6f);
  float4 gv = *(const float4*)(g  + t*4);
  float4 bv = *(const float4*)(be + t*4);
  float y0=(v0-mu)*rstd*gv.x+bv.x;
  float y1=(v1-mu)*rstd*gv.y+bv.y;
  float y2=(v2-mu)*rstd*gv.z+bv.z;
  float y3=(v3-mu)*rstd*gv.w+bv.w;
  *(float4*)(outf+rb+t*4) = make_float4(y0,y1,y2,y3);
  if (outb){
    outb[rb+t*4+0]=__float2bfloat16(y0);
    outb[rb+t*4+1]=__float2bfloat16(y1);
    outb[rb+t*4+2]=__float2bfloat16(y2);
    outb[rb+t*4+3]=__float2bfloat16(y3);
  }
}

extern "C" void kernel_launch(void* const* d_in, const int* in_sizes, int n_in,
                              void* d_out, int out_size, void* d_ws, size_t ws_size,
                              hipStream_t stream){
  const float* x    = (const float*)d_in[0];
  const int*   mask = (const int*)  d_in[1];
  const float* Wq   = (const float*)d_in[2];
  const float* Wk   = (const float*)d_in[3];
  const float* Wv   = (const float*)d_in[4];
  const float* Wo   = (const float*)d_in[5];
  const float* bo   = (const float*)d_in[6];
  const float* ln1g = (const float*)d_in[7];
  const float* ln1b = (const float*)d_in[8];
  const float* W1   = (const float*)d_in[9];
  const float* b1   = (const float*)d_in[10];
  const float* W2   = (const float*)d_in[11];
  const float* b2   = (const float*)d_in[12];
  const float* ln2g = (const float*)d_in[13];
  const float* ln2b = (const float*)d_in[14];

  char* ws = (char*)d_ws;
  const size_t MB = 1024*1024;
  // liveness-planned workspace (80 MB total):
  __hip_bfloat16* xb   = (__hip_bfloat16*)(ws + 0);        // 8MB   [dead after QKV]
  __hip_bfloat16* WqT  = (__hip_bfloat16*)(ws + 8*MB);     // 2MB
  __hip_bfloat16* WkT  = (__hip_bfloat16*)(ws + 10*MB);
  __hip_bfloat16* WvT  = (__hip_bfloat16*)(ws + 12*MB);
  __hip_bfloat16* WoT  = (__hip_bfloat16*)(ws + 14*MB);
  __hip_bfloat16* W1T  = (__hip_bfloat16*)(ws + 16*MB);    // 4MB
  __hip_bfloat16* W2T  = (__hip_bfloat16*)(ws + 20*MB);    // 4MB
  float* q_proj        = (float*)(ws + 24*MB);             // 16MB  [dead after ln1]
  float* k_proj        = (float*)(ws + 40*MB);             // 16MB  [dead after attn]
  float* v_proj        = (float*)(ws + 56*MB);             // 16MB  [dead after attn]
  __hip_bfloat16* attn_o = (__hip_bfloat16*)(ws + 72*MB);  // 8MB   [dead after o-proj]
  float* proj_o        = (float*)(ws + 40*MB);             // reuse k_proj
  float* h1f           = (float*)(ws + 56*MB);             // reuse v_proj
  __hip_bfloat16* h1b  = (__hip_bfloat16*)(ws + 72*MB);    // reuse attn_o
  __hip_bfloat16* ff1b = (__hip_bfloat16*)(ws + 24*MB);    // reuse q_proj (16MB)
  float* ff2           = (float*)(ws + 0);                 // reuse xb+WqT..WoT (16MB)

  // 1. prep
  cast_bf16_kernel<<<ROWS*D_MODEL/4/256, 256, 0, stream>>>(x, xb, ROWS*D_MODEL);
  transpose_cast_kernel<<<dim3(32,32), 256, 0, stream>>>(Wq, WqT, 1024, 1024);
  transpose_cast_kernel<<<dim3(32,32), 256, 0, stream>>>(Wk, WkT, 1024, 1024);
  transpose_cast_kernel<<<dim3(32,32), 256, 0, stream>>>(Wv, WvT, 1024, 1024);
  transpose_cast_kernel<<<dim3(32,32), 256, 0, stream>>>(Wo, WoT, 1024, 1024);
  transpose_cast_kernel<<<dim3(64,32), 256, 0, stream>>>(W1, W1T, 1024, 2048);
  transpose_cast_kernel<<<dim3(32,64), 256, 0, stream>>>(W2, W2T, 2048, 1024);

  // 2. QKV projections (f32 out)
  gemm_bt_kernel<0><<<dim3(8,32), 256, 0, stream>>>((const u16*)xb, (const u16*)WqT, nullptr, q_proj, ROWS, 1024, 1024);
  gemm_bt_kernel<0><<<dim3(8,32), 256, 0, stream>>>((const u16*)xb, (const u16*)WkT, nullptr, k_proj, ROWS, 1024, 1024);
  gemm_bt_kernel<0><<<dim3(8,32), 256, 0, stream>>>((const u16*)xb, (const u16*)WvT, nullptr, v_proj, ROWS, 1024, 1024);

  // 3. attention (bf16 out)
  attn_kernel<<<BATCH*N_HEADS*(SEQ/4), 64, 0, stream>>>(q_proj, k_proj, v_proj, mask, attn_o);

  // 4. output projection (+bo)
  gemm_bt_kernel<0><<<dim3(8,32), 256, 0, stream>>>((const u16*)attn_o, (const u16*)WoT, bo, proj_o, ROWS, 1024, 1024);

  // 5. ln1: h1 = LN(relu(proj_o) + q_proj)
  ln_fused_kernel<<<ROWS, 256, 0, stream>>>(proj_o, q_proj, ln1g, ln1b, h1f, h1b);

  // 6. FFN1 (+b1, bf16 out, no activation here)
  gemm_bt_kernel<1><<<dim3(16,32), 256, 0, stream>>>((const u16*)h1b, (const u16*)W1T, b1, ff1b, ROWS, 2048, 1024);

  // 7. FFN2 (+b2, f32 out)
  gemm_bt_kernel<0><<<dim3(8,32), 256, 0, stream>>>((const u16*)ff1b, (const u16*)W2T, b2, ff2, ROWS, 1024, 2048);

  // 8. ln2: y = LN(relu(ff2) + h1)
  ln_fused_kernel<<<ROWS, 256, 0, stream>>>(ff2, h1f, ln2g, ln2b, (float*)d_out, nullptr);
}

// Round 2
// 291.349 us; speedup vs baseline: 15.0092x; 15.0092x over previous
//
#include <hip/hip_runtime.h>
#include <hip/hip_bf16.h>

#define D_MODEL 1024
#define N_HEADS 16
#define D_HEAD  64
#define D_FF    2048
#define BATCH   4
#define SEQ     1024
#define ROWS    (BATCH*SEQ)   // 4096

typedef __bf16  bf16x8 __attribute__((ext_vector_type(8)));
typedef float   f32x4  __attribute__((ext_vector_type(4)));
typedef unsigned int u32x4 __attribute__((ext_vector_type(4)));
typedef unsigned short u16;

__device__ inline u16 f2bf(float x){ __hip_bfloat16 b = __float2bfloat16(x); return *(u16*)&b; }

// ---------------- prep: f32 -> bf16 cast ----------------
__global__ __launch_bounds__(256)
void cast_bf16_kernel(const float* __restrict__ src, __hip_bfloat16* __restrict__ dst, int n){
  int i = (blockIdx.x*blockDim.x + threadIdx.x)*4;
  if (i + 3 < n){
    float4 v = *(const float4*)(src + i);
    dst[i+0] = __float2bfloat16(v.x);
    dst[i+1] = __float2bfloat16(v.y);
    dst[i+2] = __float2bfloat16(v.z);
    dst[i+3] = __float2bfloat16(v.w);
  }
}

// ---------------- prep: transpose + cast (W[R][C] -> WT[C][R] bf16) ----------------
__global__ __launch_bounds__(256)
void transpose_cast_kernel(const float* __restrict__ src, __hip_bfloat16* __restrict__ dst,
                           int R, int C){
  __shared__ float tile[32][33];
  int c0 = blockIdx.x*32, r0 = blockIdx.y*32;
  int tx = threadIdx.x & 31, ty = threadIdx.x >> 5;
  #pragma unroll
  for (int i=0;i<32;i+=8)
    tile[ty+i][tx] = src[(size_t)(r0+ty+i)*C + (c0+tx)];
  __syncthreads();
  #pragma unroll
  for (int i=0;i<32;i+=8)
    dst[(size_t)(c0+ty+i)*R + (r0+tx)] = __float2bfloat16(tile[tx][ty+i]);
}

// ---------------- bf16 MFMA GEMM: C[M][N] = A[M][K] @ BT[N][K]^T
// MODE: 0=f32 flat, 1=bf16 flat, 2=f32 flat + scaled bf16 head-major [B,H,S,64],
//       3=bf16 head-major, 4=bf16 d-major [B,H,64,S]
template<int MODE>
__global__ __launch_bounds__(256, 2)
void gemm_bt_kernel(const u16* __restrict__ A, const u16* __restrict__ BT,
                    const float* __restrict__ bias, float* __restrict__ Cf,
                    __hip_bfloat16* __restrict__ Cb, int M, int N, int K, float cscale){
  __shared__ u16 As[128][40];
  __shared__ u16 Bs[128][40];
  const int m0 = blockIdx.y*128, n0 = blockIdx.x*128;
  const int t = threadIdx.x;
  const int wid = t>>6, lane = t&63;
  const int wm = wid>>1, wn = wid&1;
  const int lr = lane&15, lk = (lane>>4)*8;

  f32x4 acc[4][4] = {};

  for (int kt=0; kt<K; kt+=32){
    __syncthreads();
    #pragma unroll
    for (int it=0; it<2; ++it){
      int idx = it*256 + t;
      int row = idx>>2, seg = idx&3;
      u32x4 va = *(const u32x4*)(A  + (size_t)(m0+row)*K + kt + seg*8);
      *(u32x4*)&As[row][seg*8] = va;
      u32x4 vb = *(const u32x4*)(BT + (size_t)(n0+row)*K + kt + seg*8);
      *(u32x4*)&Bs[row][seg*8] = vb;
    }
    __syncthreads();
    bf16x8 af[4], bfr[4];
    #pragma unroll
    for (int f=0; f<4; ++f){
      af[f]  = *(const bf16x8*)&As[wm*64 + f*16 + lr][lk];
      bfr[f] = *(const bf16x8*)&Bs[wn*64 + f*16 + lr][lk];
    }
    #pragma unroll
    for (int i=0;i<4;++i)
      #pragma unroll
      for (int j=0;j<4;++j)
        acc[i][j] = __builtin_amdgcn_mfma_f32_16x16x32_bf16(af[i], bfr[j], acc[i][j], 0,0,0);
  }

  const int r_in = (lane>>4)*4;
  #pragma unroll
  for (int i=0;i<4;++i){
    #pragma unroll
    for (int j=0;j<4;++j){
      int col = n0 + wn*64 + j*16 + lr;
      float bv = bias ? bias[col] : 0.f;
      #pragma unroll
      for (int e=0;e<4;++e){
        int row = m0 + wm*64 + i*16 + r_in + e;
        float v = acc[i][j][e] + bv;
        if (MODE == 0){
          Cf[(size_t)row*N + col] = v;
        } else if (MODE == 1){
          Cb[(size_t)row*N + col] = __float2bfloat16(v);
        } else if (MODE == 2){
          Cf[(size_t)row*N + col] = v;
          size_t hm = (((size_t)(row>>10)*16 + (col>>6))*1024 + (row&1023))*64 + (col&63);
          Cb[hm] = __float2bfloat16(v * cscale);
        } else if (MODE == 3){
          size_t hm = (((size_t)(row>>10)*16 + (col>>6))*1024 + (row&1023))*64 + (col&63);
          Cb[hm] = __float2bfloat16(v);
        } else { // MODE == 4: [B,H,64,S]
          size_t dm = (((size_t)(row>>10)*16 + (col>>6))*64 + (col&63))*1024 + (row&1023);
          Cb[dm] = __float2bfloat16(v);
        }
      }
    }
  }
}

// ---------------- MFMA flash attention ----------------
// qb: [B,H,S,64] bf16, pre-scaled by 1/sqrt(D_MODEL); kb: [B,H,S,64]; vt: [B,H,64,S]
// out: [B,S,D_MODEL] bf16. Block = 4 waves; wave w owns 16 q-rows; 64-key tiles.
__global__ __launch_bounds__(256)
void attn_mfma_kernel(const u16* __restrict__ qb, const u16* __restrict__ kb,
                      const u16* __restrict__ vt, const int* __restrict__ mask,
                      __hip_bfloat16* __restrict__ out){
  __shared__ u16 Ks[64*72];
  __shared__ u16 Vs[64*72];
  __shared__ u16 Pl[4][16*72];
  const int t = threadIdx.x;
  const int wid = t>>6, lane = t&63;
  const int lr = lane&15, lg = lane>>4, lk = lg*8;
  const int bh = blockIdx.y;
  const int b = bh>>4, h = bh&15;
  const int q0 = blockIdx.x*64 + wid*16;
  const u16* qbase = qb + (size_t)bh*1024*64;
  const u16* kbase = kb + (size_t)bh*1024*64;
  const u16* vbase = vt + (size_t)bh*64*1024;
  const int* mrow = mask + b*SEQ;

  bf16x8 aq[2];
  aq[0] = *(const bf16x8*)(qbase + (size_t)(q0+lr)*64 + lk);
  aq[1] = *(const bf16x8*)(qbase + (size_t)(q0+lr)*64 + 32 + lk);

  f32x4 osum[4] = {};
  float m_run[4], l_run[4];
  #pragma unroll
  for (int e=0;e<4;++e){ m_run[e]=-1e30f; l_run[e]=0.f; }

  for (int kt=0; kt<SEQ/64; ++kt){
    const int k0 = kt*64;
    __syncthreads();
    #pragma unroll
    for (int p=0;p<2;++p){
      int r = p*32 + (t>>3), sg = (t&7)*8;
      *(u32x4*)&Ks[r*72+sg] = *(const u32x4*)(kbase + (size_t)(k0+r)*64 + sg);
      *(u32x4*)&Vs[r*72+sg] = *(const u32x4*)(vbase + (size_t)r*1024 + k0 + sg);
    }
    __syncthreads();

    // QK^T: S tile 16q x 64k per wave
    f32x4 sacc[4] = {};
    #pragma unroll
    for (int k4=0;k4<4;++k4){
      #pragma unroll
      for (int dg=0;dg<2;++dg){
        bf16x8 kf = *(const bf16x8*)&Ks[(k4*16+lr)*72 + dg*32 + lk];
        sacc[k4] = __builtin_amdgcn_mfma_f32_16x16x32_bf16(aq[dg], kf, sacc[k4],0,0,0);
      }
    }
    // mask (key depends only on lane&15 per 16-tile)
    #pragma unroll
    for (int k4=0;k4<4;++k4){
      if (mrow[k0 + k4*16 + lr] == 0){
        #pragma unroll
        for (int e=0;e<4;++e) sacc[k4][e] = -1e30f;
      }
    }
    // online softmax per q-row e (row spread over 16-lane group: xor 1,2,4,8)
    #pragma unroll
    for (int e=0;e<4;++e){
      float tm = fmaxf(fmaxf(sacc[0][e],sacc[1][e]),fmaxf(sacc[2][e],sacc[3][e]));
      tm = fmaxf(tm, __shfl_xor(tm,1)); tm = fmaxf(tm, __shfl_xor(tm,2));
      tm = fmaxf(tm, __shfl_xor(tm,4)); tm = fmaxf(tm, __shfl_xor(tm,8));
      float mn = fmaxf(m_run[e], tm);
      float c  = __expf(m_run[e]-mn);
      m_run[e] = mn;
      float ps = 0.f;
      #pragma unroll
      for (int k4=0;k4<4;++k4){ float p = __expf(sacc[k4][e]-mn); sacc[k4][e]=p; ps+=p; }
      ps += __shfl_xor(ps,1); ps += __shfl_xor(ps,2); ps += __shfl_xor(ps,4); ps += __shfl_xor(ps,8);
      l_run[e] = l_run[e]*c + ps;
      #pragma unroll
      for (int dt=0;dt<4;++dt) osum[dt][e] *= c;
    }
    // P (C/D layout) -> LDS -> A-frag layout
    #pragma unroll
    for (int k4=0;k4<4;++k4)
      #pragma unroll
      for (int e=0;e<4;++e)
        Pl[wid][(lg*4+e)*72 + k4*16 + lr] = f2bf(sacc[k4][e]);
    // PV: O tile 16q x 64d per wave
    #pragma unroll
    for (int dt=0;dt<4;++dt){
      #pragma unroll
      for (int kg=0;kg<2;++kg){
        bf16x8 pa = *(const bf16x8*)&Pl[wid][lr*72 + kg*32 + lk];
        bf16x8 vf = *(const bf16x8*)&Vs[(dt*16+lr)*72 + kg*32 + lk];
        osum[dt] = __builtin_amdgcn_mfma_f32_16x16x32_bf16(pa, vf, osum[dt],0,0,0);
      }
    }
  }
  // epilogue -> [B,S,D_MODEL] bf16
  #pragma unroll
  for (int dt=0;dt<4;++dt){
    int d = dt*16 + lr;
    #pragma unroll
    for (int e=0;e<4;++e){
      int q = q0 + lg*4 + e;
      out[((size_t)b*1024 + q)*1024 + h*64 + d] = __float2bfloat16(osum[dt][e] * (1.f/l_run[e]));
    }
  }
}

// ---------------- fused: t = relu(a)+res; layernorm(t)*g+b -> outf (+ optional bf16) ----------------
__global__ __launch_bounds__(256)
void ln_fused_kernel(const float* __restrict__ a, const float* __restrict__ res,
                     const float* __restrict__ g, const float* __restrict__ be,
                     float* __restrict__ outf, __hip_bfloat16* __restrict__ outb){
  int row = blockIdx.x, t = threadIdx.x;
  size_t rb = (size_t)row*D_MODEL;
  float4 av = *(const float4*)(a  + rb + t*4);
  float4 rv = *(const float4*)(res+ rb + t*4);
  float v0 = fmaxf(av.x,0.f)+rv.x;
  float v1 = fmaxf(av.y,0.f)+rv.y;
  float v2 = fmaxf(av.z,0.f)+rv.z;
  float v3 = fmaxf(av.w,0.f)+rv.w;
  float sum = v0+v1+v2+v3;
  float ss  = v0*v0+v1*v1+v2*v2+v3*v3;
  #pragma unroll
  for (int off=32; off; off>>=1){ sum += __shfl_xor(sum,off); ss += __shfl_xor(ss,off); }
  __shared__ float red[8];
  int wid = t>>6, lane = t&63;
  if (lane==0){ red[wid]=sum; red[4+wid]=ss; }
  __syncthreads();
  sum = red[0]+red[1]+red[2]+red[3];
  ss  = red[4]+red[5]+red[6]+red[7];
  float mu  = sum*(1.f/1024.f);
  float var = ss*(1.f/1024.f) - mu*mu;
  float rstd = rsqrtf(var + 1e-6f);
  float4 gv = *(const float4*)(g  + t*4);
  float4 bv = *(const float4*)(be + t*4);
  float y0=(v0-mu)*rstd*gv.x+bv.x;
  float y1=(v1-mu)*rstd*gv.y+bv.y;
  float y2=(v2-mu)*rstd*gv.z+bv.z;
  float y3=(v3-mu)*rstd*gv.w+bv.w;
  *(float4*)(outf+rb+t*4) = make_float4(y0,y1,y2,y3);
  if (outb){
    outb[rb+t*4+0]=__float2bfloat16(y0);
    outb[rb+t*4+1]=__float2bfloat16(y1);
    outb[rb+t*4+2]=__float2bfloat16(y2);
    outb[rb+t*4+3]=__float2bfloat16(y3);
  }
}

extern "C" void kernel_launch(void* const* d_in, const int* in_sizes, int n_in,
                              void* d_out, int out_size, void* d_ws, size_t ws_size,
                              hipStream_t stream){
  const float* x    = (const float*)d_in[0];
  const int*   mask = (const int*)  d_in[1];
  const float* Wq   = (const float*)d_in[2];
  const float* Wk   = (const float*)d_in[3];
  const float* Wv   = (const float*)d_in[4];
  const float* Wo   = (const float*)d_in[5];
  const float* bo   = (const float*)d_in[6];
  const float* ln1g = (const float*)d_in[7];
  const float* ln1b = (const float*)d_in[8];
  const float* W1   = (const float*)d_in[9];
  const float* b1   = (const float*)d_in[10];
  const float* W2   = (const float*)d_in[11];
  const float* b2   = (const float*)d_in[12];
  const float* ln2g = (const float*)d_in[13];
  const float* ln2b = (const float*)d_in[14];

  char* ws = (char*)d_ws;
  const size_t MB = 1024*1024;
  // liveness-planned workspace (72 MB max):
  __hip_bfloat16* WqT  = (__hip_bfloat16*)(ws + 0);        // 2MB
  __hip_bfloat16* WkT  = (__hip_bfloat16*)(ws + 2*MB);
  __hip_bfloat16* WvT  = (__hip_bfloat16*)(ws + 4*MB);
  __hip_bfloat16* WoT  = (__hip_bfloat16*)(ws + 6*MB);
  __hip_bfloat16* W1T  = (__hip_bfloat16*)(ws + 8*MB);     // 4MB
  __hip_bfloat16* W2T  = (__hip_bfloat16*)(ws + 12*MB);    // 4MB
  __hip_bfloat16* xb   = (__hip_bfloat16*)(ws + 16*MB);    // 8MB  [dead after QKV]
  float* q_proj        = (float*)(ws + 24*MB);             // 16MB [dead after ln1]
  __hip_bfloat16* qb   = (__hip_bfloat16*)(ws + 40*MB);    // 8MB  [dead after attn]
  __hip_bfloat16* kb   = (__hip_bfloat16*)(ws + 48*MB);    // 8MB  [dead after attn]
  __hip_bfloat16* vt   = (__hip_bfloat16*)(ws + 56*MB);    // 8MB  [dead after attn]
  __hip_bfloat16* attn_o = (__hip_bfloat16*)(ws + 64*MB);  // 8MB  [dead after o-proj]
  float* proj_o        = (float*)(ws + 40*MB);             // reuse qb+kb   [dead after ln1]
  float* h1f           = (float*)(ws + 56*MB);             // reuse vt+attn_o [live till ln2]
  __hip_bfloat16* h1b  = (__hip_bfloat16*)(ws + 16*MB);    // reuse xb
  __hip_bfloat16* ff1b = (__hip_bfloat16*)(ws + 24*MB);    // reuse q_proj (16MB)
  float* ff2           = (float*)(ws + 40*MB);             // reuse proj_o (16MB)

  const float qscale = 0.03125f; // 1/sqrt(D_MODEL)

  // 1. prep
  cast_bf16_kernel<<<ROWS*D_MODEL/4/256, 256, 0, stream>>>(x, xb, ROWS*D_MODEL);
  transpose_cast_kernel<<<dim3(32,32), 256, 0, stream>>>(Wq, WqT, 1024, 1024);
  transpose_cast_kernel<<<dim3(32,32), 256, 0, stream>>>(Wk, WkT, 1024, 1024);
  transpose_cast_kernel<<<dim3(32,32), 256, 0, stream>>>(Wv, WvT, 1024, 1024);
  transpose_cast_kernel<<<dim3(32,32), 256, 0, stream>>>(Wo, WoT, 1024, 1024);
  transpose_cast_kernel<<<dim3(64,32), 256, 0, stream>>>(W1, W1T, 1024, 2048);
  transpose_cast_kernel<<<dim3(32,64), 256, 0, stream>>>(W2, W2T, 2048, 1024);

  // 2. QKV projections
  gemm_bt_kernel<2><<<dim3(8,32), 256, 0, stream>>>((const u16*)xb, (const u16*)WqT, nullptr, q_proj, qb, ROWS, 1024, 1024, qscale);
  gemm_bt_kernel<3><<<dim3(8,32), 256, 0, stream>>>((const u16*)xb, (const u16*)WkT, nullptr, nullptr, kb, ROWS, 1024, 1024, 1.f);
  gemm_bt_kernel<4><<<dim3(8,32), 256, 0, stream>>>((const u16*)xb, (const u16*)WvT, nullptr, nullptr, vt, ROWS, 1024, 1024, 1.f);

  // 3. MFMA flash attention
  attn_mfma_kernel<<<dim3(SEQ/64, BATCH*N_HEADS), 256, 0, stream>>>(
      (const u16*)qb, (const u16*)kb, (const u16*)vt, mask, attn_o);

  // 4. output projection (+bo)
  gemm_bt_kernel<0><<<dim3(8,32), 256, 0, stream>>>((const u16*)attn_o, (const u16*)WoT, bo, proj_o, nullptr, ROWS, 1024, 1024, 1.f);

  // 5. ln1: h1 = LN(relu(proj_o) + q_proj)
  ln_fused_kernel<<<ROWS, 256, 0, stream>>>(proj_o, q_proj, ln1g, ln1b, h1f, h1b);

  // 6. FFN1 (+b1, bf16 out)
  gemm_bt_kernel<1><<<dim3(16,32), 256, 0, stream>>>((const u16*)h1b, (const u16*)W1T, b1, nullptr, ff1b, ROWS, 2048, 1024, 1.f);

  // 7. FFN2 (+b2, f32 out)
  gemm_bt_kernel<0><<<dim3(8,32), 256, 0, stream>>>((const u16*)ff1b, (const u16*)W2T, b2, ff2, nullptr, ROWS, 1024, 2048, 1.f);

  // 8. ln2: y = LN(relu(ff2) + h1)
  ln_fused_kernel<<<ROWS, 256, 0, stream>>>(ff2, h1f, ln2g, ln2b, (float*)d_out, nullptr);
}

// Round 4
// 244.007 us; speedup vs baseline: 17.9212x; 1.1940x over previous
//
#include <hip/hip_runtime.h>
#include <hip/hip_bf16.h>

#define D_MODEL 1024
#define N_HEADS 16
#define D_HEAD  64
#define D_FF    2048
#define BATCH   4
#define SEQ     1024
#define ROWS    (BATCH*SEQ)   // 4096

typedef __bf16  bf16x8 __attribute__((ext_vector_type(8)));
typedef float   f32x4  __attribute__((ext_vector_type(4)));
typedef unsigned int u32x4 __attribute__((ext_vector_type(4)));
typedef unsigned short u16;

__device__ inline u16 f2bf(float x){ __hip_bfloat16 b = __float2bfloat16(x); return *(u16*)&b; }

// async global->LDS, 16B per lane. gsrc per-lane, ldst wave-uniform base (+lane*16 implicit).
__device__ inline void load_lds16(const u16* gsrc, u16* ldst){
  __builtin_amdgcn_global_load_lds((const __attribute__((address_space(1))) void*)gsrc,
                                   (__attribute__((address_space(3))) void*)ldst, 16, 0, 0);
}

// ---------------- prep: f32 -> bf16 cast ----------------
__global__ __launch_bounds__(256)
void cast_bf16_kernel(const float* __restrict__ src, __hip_bfloat16* __restrict__ dst, int n){
  int i = (blockIdx.x*blockDim.x + threadIdx.x)*4;
  if (i + 3 < n){
    float4 v = *(const float4*)(src + i);
    dst[i+0] = __float2bfloat16(v.x);
    dst[i+1] = __float2bfloat16(v.y);
    dst[i+2] = __float2bfloat16(v.z);
    dst[i+3] = __float2bfloat16(v.w);
  }
}

// ---------------- prep: transpose + cast (W[R][C] -> WT[C][R] bf16) ----------------
__global__ __launch_bounds__(256)
void transpose_cast_kernel(const float* __restrict__ src, __hip_bfloat16* __restrict__ dst,
                           int R, int C){
  __shared__ float tile[32][33];
  int c0 = blockIdx.x*32, r0 = blockIdx.y*32;
  int tx = threadIdx.x & 31, ty = threadIdx.x >> 5;
  #pragma unroll
  for (int i=0;i<32;i+=8)
    tile[ty+i][tx] = src[(size_t)(r0+ty+i)*C + (c0+tx)];
  __syncthreads();
  #pragma unroll
  for (int i=0;i<32;i+=8)
    dst[(size_t)(c0+ty+i)*R + (r0+tx)] = __float2bfloat16(tile[tx][ty+i]);
}

// ---------------- bf16 MFMA GEMM (m97 structure): C[M][N] = A[M][K] @ BT[N][K]^T
// 128x128 tile, BK=32, 4 waves (2x2), linear LDS, global_load_lds width=16.
// MODE: 0=f32 flat, 1=bf16 flat,
//       5=QKV fused: col<1024 -> q_proj f32 + scaled qb head-major; 1024..2047 -> kb head-major;
//                    2048..3071 -> vt d-major [B,H,64,S]. Cb points at qb (kb=+4Mi, vt=+8Mi elems).
template<int MODE>
__global__ __launch_bounds__(256, 2)
void gemm_bt_kernel(const u16* __restrict__ A, const u16* __restrict__ BT,
                    const float* __restrict__ bias, float* __restrict__ Cf,
                    __hip_bfloat16* __restrict__ Cb, int M, int N, int K, float cscale){
  __shared__ u16 As[128*32];
  __shared__ u16 Bs[128*32];
  const int m0 = blockIdx.y*128, n0 = blockIdx.x*128;
  const int t = threadIdx.x;
  const int wid = t>>6, lane = t&63;
  const int wm = wid>>1, wn = wid&1;
  const int lr = lane&15, lk = (lane>>4)*8;
  // staging geometry: call c covers rows c*64..c*64+63; thread t -> row c*64+(t>>2), seg (t&3)*8
  const int srow = t>>2, sseg = (t&3)*8;
  const int wbase = wid*512;  // u16 offset of this wave's 1KB chunk within a 4KB call

  f32x4 acc[4][4] = {};

  for (int kt=0; kt<K; kt+=32){
    __syncthreads();
    #pragma unroll
    for (int c=0;c<2;++c){
      load_lds16(A  + (size_t)(m0 + c*64 + srow)*K + kt + sseg, &As[c*2048 + wbase]);
      load_lds16(BT + (size_t)(n0 + c*64 + srow)*K + kt + sseg, &Bs[c*2048 + wbase]);
    }
    __syncthreads();
    bf16x8 af[4], bfr[4];
    #pragma unroll
    for (int f=0; f<4; ++f){
      af[f]  = *(const bf16x8*)&As[(wm*64 + f*16 + lr)*32 + lk];
      bfr[f] = *(const bf16x8*)&Bs[(wn*64 + f*16 + lr)*32 + lk];
    }
    #pragma unroll
    for (int i=0;i<4;++i)
      #pragma unroll
      for (int j=0;j<4;++j)
        acc[i][j] = __builtin_amdgcn_mfma_f32_16x16x32_bf16(af[i], bfr[j], acc[i][j], 0,0,0);
  }

  const int r_in = (lane>>4)*4;
  #pragma unroll
  for (int i=0;i<4;++i){
    #pragma unroll
    for (int j=0;j<4;++j){
      int col = n0 + wn*64 + j*16 + lr;
      float bv = bias ? bias[col] : 0.f;
      #pragma unroll
      for (int e=0;e<4;++e){
        int row = m0 + wm*64 + i*16 + r_in + e;
        float v = acc[i][j][e] + bv;
        if (MODE == 0){
          Cf[(size_t)row*N + col] = v;
        } else if (MODE == 1){
          Cb[(size_t)row*N + col] = __float2bfloat16(v);
        } else { // MODE 5: QKV fused epilogue (which is block-uniform)
          int b = row>>10, s = row&1023;
          int which = col>>10, c = col&1023, h = c>>6, d = c&63;
          size_t hm = (((size_t)b*16 + h)*1024 + s)*64 + d;
          if (which == 0){
            Cf[(size_t)row*1024 + c] = v;
            Cb[hm] = __float2bfloat16(v * cscale);
          } else if (which == 1){
            Cb[4194304u + hm] = __float2bfloat16(v);
          } else {
            Cb[8388608u + (((size_t)b*16 + h)*64 + d)*1024 + s] = __float2bfloat16(v);
          }
        }
      }
    }
  }
}

// ---------------- MFMA flash attention ----------------
// qb: [B,H,S,64] bf16 pre-scaled; kb: [B,H,S,64]; vt: [B,H,64,S]
__global__ __launch_bounds__(256)
void attn_mfma_kernel(const u16* __restrict__ qb, const u16* __restrict__ kb,
                      const u16* __restrict__ vt, const int* __restrict__ mask,
                      __hip_bfloat16* __restrict__ out){
  __shared__ u16 Ks[64*72];
  __shared__ u16 Vs[64*72];
  __shared__ u16 Pl[4][16*72];
  const int t = threadIdx.x;
  const int wid = t>>6, lane = t&63;
  const int lr = lane&15, lg = lane>>4, lk = lg*8;
  const int bh = blockIdx.y;
  const int b = bh>>4, h = bh&15;
  const int q0 = blockIdx.x*64 + wid*16;
  const u16* qbase = qb + (size_t)bh*1024*64;
  const u16* kbase = kb + (size_t)bh*1024*64;
  const u16* vbase = vt + (size_t)bh*64*1024;
  const int* mrow = mask + b*SEQ;

  bf16x8 aq[2];
  aq[0] = *(const bf16x8*)(qbase + (size_t)(q0+lr)*64 + lk);
  aq[1] = *(const bf16x8*)(qbase + (size_t)(q0+lr)*64 + 32 + lk);

  f32x4 osum[4] = {};
  float m_run[4], l_run[4];
  #pragma unroll
  for (int e=0;e<4;++e){ m_run[e]=-1e30f; l_run[e]=0.f; }

  for (int kt=0; kt<SEQ/64; ++kt){
    const int k0 = kt*64;
    __syncthreads();
    #pragma unroll
    for (int p=0;p<2;++p){
      int r = p*32 + (t>>3), sg = (t&7)*8;
      *(u32x4*)&Ks[r*72+sg] = *(const u32x4*)(kbase + (size_t)(k0+r)*64 + sg);
      *(u32x4*)&Vs[r*72+sg] = *(const u32x4*)(vbase + (size_t)r*1024 + k0 + sg);
    }
    __syncthreads();

    f32x4 sacc[4] = {};
    #pragma unroll
    for (int k4=0;k4<4;++k4){
      #pragma unroll
      for (int dg=0;dg<2;++dg){
        bf16x8 kf = *(const bf16x8*)&Ks[(k4*16+lr)*72 + dg*32 + lk];
        sacc[k4] = __builtin_amdgcn_mfma_f32_16x16x32_bf16(aq[dg], kf, sacc[k4],0,0,0);
      }
    }
    #pragma unroll
    for (int k4=0;k4<4;++k4){
      if (mrow[k0 + k4*16 + lr] == 0){
        #pragma unroll
        for (int e=0;e<4;++e) sacc[k4][e] = -1e30f;
      }
    }
    #pragma unroll
    for (int e=0;e<4;++e){
      float tm = fmaxf(fmaxf(sacc[0][e],sacc[1][e]),fmaxf(sacc[2][e],sacc[3][e]));
      tm = fmaxf(tm, __shfl_xor(tm,1)); tm = fmaxf(tm, __shfl_xor(tm,2));
      tm = fmaxf(tm, __shfl_xor(tm,4)); tm = fmaxf(tm, __shfl_xor(tm,8));
      float mn = fmaxf(m_run[e], tm);
      float c  = __expf(m_run[e]-mn);
      m_run[e] = mn;
      float ps = 0.f;
      #pragma unroll
      for (int k4=0;k4<4;++k4){ float p = __expf(sacc[k4][e]-mn); sacc[k4][e]=p; ps+=p; }
      ps += __shfl_xor(ps,1); ps += __shfl_xor(ps,2); ps += __shfl_xor(ps,4); ps += __shfl_xor(ps,8);
      l_run[e] = l_run[e]*c + ps;
      #pragma unroll
      for (int dt=0;dt<4;++dt) osum[dt][e] *= c;
    }
    #pragma unroll
    for (int k4=0;k4<4;++k4)
      #pragma unroll
      for (int e=0;e<4;++e)
        Pl[wid][(lg*4+e)*72 + k4*16 + lr] = f2bf(sacc[k4][e]);
    #pragma unroll
    for (int dt=0;dt<4;++dt){
      #pragma unroll
      for (int kg=0;kg<2;++kg){
        bf16x8 pa = *(const bf16x8*)&Pl[wid][lr*72 + kg*32 + lk];
        bf16x8 vf = *(const bf16x8*)&Vs[(dt*16+lr)*72 + kg*32 + lk];
        osum[dt] = __builtin_amdgcn_mfma_f32_16x16x32_bf16(pa, vf, osum[dt],0,0,0);
      }
    }
  }
  #pragma unroll
  for (int dt=0;dt<4;++dt){
    int d = dt*16 + lr;
    #pragma unroll
    for (int e=0;e<4;++e){
      int q = q0 + lg*4 + e;
      out[((size_t)b*1024 + q)*1024 + h*64 + d] = __float2bfloat16(osum[dt][e] * (1.f/l_run[e]));
    }
  }
}

// ---------------- fused: t = relu(a)+res; layernorm(t)*g+b ----------------
__global__ __launch_bounds__(256)
void ln_fused_kernel(const float* __restrict__ a, const float* __restrict__ res,
                     const float* __restrict__ g, const float* __restrict__ be,
                     float* __restrict__ outf, __hip_bfloat16* __restrict__ outb){
  int row = blockIdx.x, t = threadIdx.x;
  size_t rb = (size_t)row*D_MODEL;
  float4 av = *(const float4*)(a  + rb + t*4);
  float4 rv = *(const float4*)(res+ rb + t*4);
  float v0 = fmaxf(av.x,0.f)+rv.x;
  float v1 = fmaxf(av.y,0.f)+rv.y;
  float v2 = fmaxf(av.z,0.f)+rv.z;
  float v3 = fmaxf(av.w,0.f)+rv.w;
  float sum = v0+v1+v2+v3;
  float ss  = v0*v0+v1*v1+v2*v2+v3*v3;
  #pragma unroll
  for (int off=32; off; off>>=1){ sum += __shfl_xor(sum,off); ss += __shfl_xor(ss,off); }
  __shared__ float red[8];
  int wid = t>>6, lane = t&63;
  if (lane==0){ red[wid]=sum; red[4+wid]=ss; }
  __syncthreads();
  sum = red[0]+red[1]+red[2]+red[3];
  ss  = red[4]+red[5]+red[6]+red[7];
  float mu  = sum*(1.f/1024.f);
  float var = ss*(1.f/1024.f) - mu*mu;
  float rstd = rsqrtf(var + 1e-6f);
  float4 gv = *(const float4*)(g  + t*4);
  float4 bv = *(const float4*)(be + t*4);
  float y0=(v0-mu)*rstd*gv.x+bv.x;
  float y1=(v1-mu)*rstd*gv.y+bv.y;
  float y2=(v2-mu)*rstd*gv.z+bv.z;
  float y3=(v3-mu)*rstd*gv.w+bv.w;
  *(float4*)(outf+rb+t*4) = make_float4(y0,y1,y2,y3);
  if (outb){
    outb[rb+t*4+0]=__float2bfloat16(y0);
    outb[rb+t*4+1]=__float2bfloat16(y1);
    outb[rb+t*4+2]=__float2bfloat16(y2);
    outb[rb+t*4+3]=__float2bfloat16(y3);
  }
}

extern "C" void kernel_launch(void* const* d_in, const int* in_sizes, int n_in,
                              void* d_out, int out_size, void* d_ws, size_t ws_size,
                              hipStream_t stream){
  const float* x    = (const float*)d_in[0];
  const int*   mask = (const int*)  d_in[1];
  const float* Wq   = (const float*)d_in[2];
  const float* Wk   = (const float*)d_in[3];
  const float* Wv   = (const float*)d_in[4];
  const float* Wo   = (const float*)d_in[5];
  const float* bo   = (const float*)d_in[6];
  const float* ln1g = (const float*)d_in[7];
  const float* ln1b = (const float*)d_in[8];
  const float* W1   = (const float*)d_in[9];
  const float* b1   = (const float*)d_in[10];
  const float* W2   = (const float*)d_in[11];
  const float* b2   = (const float*)d_in[12];
  const float* ln2g = (const float*)d_in[13];
  const float* ln2b = (const float*)d_in[14];

  char* ws = (char*)d_ws;
  const size_t MB = 1024*1024;
  // WqT/WkT/WvT are contiguous -> one [3072][1024] BT for the fused QKV GEMM
  __hip_bfloat16* WqT  = (__hip_bfloat16*)(ws + 0);        // 2MB
  __hip_bfloat16* WkT  = (__hip_bfloat16*)(ws + 2*MB);     // 2MB
  __hip_bfloat16* WvT  = (__hip_bfloat16*)(ws + 4*MB);     // 2MB
  __hip_bfloat16* WoT  = (__hip_bfloat16*)(ws + 6*MB);     // 2MB
  __hip_bfloat16* W1T  = (__hip_bfloat16*)(ws + 8*MB);     // 4MB
  __hip_bfloat16* W2T  = (__hip_bfloat16*)(ws + 12*MB);    // 4MB
  __hip_bfloat16* xb   = (__hip_bfloat16*)(ws + 16*MB);    // 8MB  [dead after QKV]
  float* q_proj        = (float*)(ws + 24*MB);             // 16MB [dead after ln1]
  __hip_bfloat16* qb   = (__hip_bfloat16*)(ws + 40*MB);    // 8MB; kb at +8MB, vt at +16MB
  __hip_bfloat16* attn_o = (__hip_bfloat16*)(ws + 64*MB);  // 8MB  [dead after o-proj]
  float* proj_o        = (float*)(ws + 40*MB);             // reuse qb+kb  [dead after ln1]
  float* h1f           = (float*)(ws + 56*MB);             // reuse vt+attn_o [live till ln2]
  __hip_bfloat16* h1b  = (__hip_bfloat16*)(ws + 16*MB);    // reuse xb
  __hip_bfloat16* ff1b = (__hip_bfloat16*)(ws + 24*MB);    // reuse q_proj (16MB)
  float* ff2           = (float*)(ws + 40*MB);             // reuse proj_o (16MB)

  const float qscale = 0.03125f; // 1/sqrt(D_MODEL)

  // 1. prep
  cast_bf16_kernel<<<ROWS*D_MODEL/4/256, 256, 0, stream>>>(x, xb, ROWS*D_MODEL);
  transpose_cast_kernel<<<dim3(32,32), 256, 0, stream>>>(Wq, WqT, 1024, 1024);
  transpose_cast_kernel<<<dim3(32,32), 256, 0, stream>>>(Wk, WkT, 1024, 1024);
  transpose_cast_kernel<<<dim3(32,32), 256, 0, stream>>>(Wv, WvT, 1024, 1024);
  transpose_cast_kernel<<<dim3(32,32), 256, 0, stream>>>(Wo, WoT, 1024, 1024);
  transpose_cast_kernel<<<dim3(64,32), 256, 0, stream>>>(W1, W1T, 1024, 2048);
  transpose_cast_kernel<<<dim3(32,64), 256, 0, stream>>>(W2, W2T, 2048, 1024);

  // 2. fused QKV projection: N=3072, epilogue routes q/k/v
  gemm_bt_kernel<5><<<dim3(24,32), 256, 0, stream>>>((const u16*)xb, (const u16*)WqT, nullptr,
                                                     q_proj, qb, ROWS, 3072, 1024, qscale);

  // 3. MFMA flash attention
  attn_mfma_kernel<<<dim3(SEQ/64, BATCH*N_HEADS), 256, 0, stream>>>(
      (const u16*)qb, (const u16*)(qb + 4194304u), (const u16*)(qb + 8388608u), mask, attn_o);

  // 4. output projection (+bo)
  gemm_bt_kernel<0><<<dim3(8,32), 256, 0, stream>>>((const u16*)attn_o, (const u16*)WoT, bo,
                                                    proj_o, nullptr, ROWS, 1024, 1024, 1.f);

  // 5. ln1: h1 = LN(relu(proj_o) + q_proj)
  ln_fused_kernel<<<ROWS, 256, 0, stream>>>(proj_o, q_proj, ln1g, ln1b, h1f, h1b);

  // 6. FFN1 (+b1, bf16 out)
  gemm_bt_kernel<1><<<dim3(16,32), 256, 0, stream>>>((const u16*)h1b, (const u16*)W1T, b1,
                                                     nullptr, ff1b, ROWS, 2048, 1024, 1.f);

  // 7. FFN2 (+b2, f32 out)
  gemm_bt_kernel<0><<<dim3(8,32), 256, 0, stream>>>((const u16*)ff1b, (const u16*)W2T, b2,
                                                    ff2, nullptr, ROWS, 1024, 2048, 1.f);

  // 8. ln2: y = LN(relu(ff2) + h1)
  ln_fused_kernel<<<ROWS, 256, 0, stream>>>(ff2, h1f, ln2g, ln2b, (float*)d_out, nullptr);
}

// Round 5
// 227.980 us; speedup vs baseline: 19.1811x; 1.0703x over previous
//
#include <hip/hip_runtime.h>
#include <hip/hip_bf16.h>

#define D_MODEL 1024
#define N_HEADS 16
#define D_HEAD  64
#define D_FF    2048
#define BATCH   4
#define SEQ     1024
#define ROWS    (BATCH*SEQ)   // 4096

typedef __bf16  bf16x8 __attribute__((ext_vector_type(8)));
typedef float   f32x4  __attribute__((ext_vector_type(4)));
typedef unsigned int u32x4 __attribute__((ext_vector_type(4)));
typedef unsigned int u32x2 __attribute__((ext_vector_type(2)));
typedef unsigned short u16;
typedef unsigned int u32;

__device__ inline u16 f2bf(float x){ __hip_bfloat16 b = __float2bfloat16(x); return *(u16*)&b; }

// async global->LDS, 16B per lane. gsrc per-lane, ldst wave-uniform base (+lane*16 implicit).
__device__ inline void load_lds16(const u16* gsrc, u16* ldst){
  __builtin_amdgcn_global_load_lds((const __attribute__((address_space(1))) void*)gsrc,
                                   (__attribute__((address_space(3))) void*)ldst, 16, 0, 0);
}

// ---------------- prep: f32 -> bf16 cast ----------------
__global__ __launch_bounds__(256)
void cast_bf16_kernel(const float* __restrict__ src, __hip_bfloat16* __restrict__ dst, int n){
  int i = (blockIdx.x*blockDim.x + threadIdx.x)*4;
  if (i + 3 < n){
    float4 v = *(const float4*)(src + i);
    dst[i+0] = __float2bfloat16(v.x);
    dst[i+1] = __float2bfloat16(v.y);
    dst[i+2] = __float2bfloat16(v.z);
    dst[i+3] = __float2bfloat16(v.w);
  }
}

// ---------------- prep: transpose + cast (W[R][C] -> WT[C][R] bf16) ----------------
__global__ __launch_bounds__(256)
void transpose_cast_kernel(const float* __restrict__ src, __hip_bfloat16* __restrict__ dst,
                           int R, int C){
  __shared__ float tile[32][33];
  int c0 = blockIdx.x*32, r0 = blockIdx.y*32;
  int tx = threadIdx.x & 31, ty = threadIdx.x >> 5;
  #pragma unroll
  for (int i=0;i<32;i+=8)
    tile[ty+i][tx] = src[(size_t)(r0+ty+i)*C + (c0+tx)];
  __syncthreads();
  #pragma unroll
  for (int i=0;i<32;i+=8)
    dst[(size_t)(c0+ty+i)*R + (r0+tx)] = __float2bfloat16(tile[tx][ty+i]);
}

// ---------------- bf16 MFMA GEMM (m97 structure): C[M][N] = A[M][K] @ BT[N][K]^T
// 128x128 tile, BK=32, 4 waves (2x2), linear LDS, global_load_lds width=16.
// MODE: 0=f32 flat, 1=bf16 flat,
//       5=QKV fused: col<1024 -> q_proj f32 + scaled qb head-major; 1024..2047 -> kb head-major;
//                    2048..3071 -> vt d-major [B,H,64,S]. Cb points at qb (kb=+4Mi, vt=+8Mi elems).
template<int MODE>
__global__ __launch_bounds__(256, 2)
void gemm_bt_kernel(const u16* __restrict__ A, const u16* __restrict__ BT,
                    const float* __restrict__ bias, float* __restrict__ Cf,
                    __hip_bfloat16* __restrict__ Cb, int M, int N, int K, float cscale){
  __shared__ u16 As[128*32];
  __shared__ u16 Bs[128*32];
  const int m0 = blockIdx.y*128, n0 = blockIdx.x*128;
  const int t = threadIdx.x;
  const int wid = t>>6, lane = t&63;
  const int wm = wid>>1, wn = wid&1;
  const int lr = lane&15, lk = (lane>>4)*8;
  const int srow = t>>2, sseg = (t&3)*8;
  const int wbase = wid*512;

  f32x4 acc[4][4] = {};

  for (int kt=0; kt<K; kt+=32){
    __syncthreads();
    #pragma unroll
    for (int c=0;c<2;++c){
      load_lds16(A  + (size_t)(m0 + c*64 + srow)*K + kt + sseg, &As[c*2048 + wbase]);
      load_lds16(BT + (size_t)(n0 + c*64 + srow)*K + kt + sseg, &Bs[c*2048 + wbase]);
    }
    __syncthreads();
    bf16x8 af[4], bfr[4];
    #pragma unroll
    for (int f=0; f<4; ++f){
      af[f]  = *(const bf16x8*)&As[(wm*64 + f*16 + lr)*32 + lk];
      bfr[f] = *(const bf16x8*)&Bs[(wn*64 + f*16 + lr)*32 + lk];
    }
    #pragma unroll
    for (int i=0;i<4;++i)
      #pragma unroll
      for (int j=0;j<4;++j)
        acc[i][j] = __builtin_amdgcn_mfma_f32_16x16x32_bf16(af[i], bfr[j], acc[i][j], 0,0,0);
  }

  const int r_in = (lane>>4)*4;
  #pragma unroll
  for (int i=0;i<4;++i){
    #pragma unroll
    for (int j=0;j<4;++j){
      int col = n0 + wn*64 + j*16 + lr;
      float bv = bias ? bias[col] : 0.f;
      #pragma unroll
      for (int e=0;e<4;++e){
        int row = m0 + wm*64 + i*16 + r_in + e;
        float v = acc[i][j][e] + bv;
        if (MODE == 0){
          Cf[(size_t)row*N + col] = v;
        } else if (MODE == 1){
          Cb[(size_t)row*N + col] = __float2bfloat16(v);
        } else { // MODE 5: QKV fused epilogue (which is block-uniform)
          int b = row>>10, s = row&1023;
          int which = col>>10, c = col&1023, h = c>>6, d = c&63;
          size_t hm = (((size_t)b*16 + h)*1024 + s)*64 + d;
          if (which == 0){
            Cf[(size_t)row*1024 + c] = v;
            Cb[hm] = __float2bfloat16(v * cscale);
          } else if (which == 1){
            Cb[4194304u + hm] = __float2bfloat16(v);
          } else {
            Cb[8388608u + (((size_t)b*16 + h)*64 + d)*1024 + s] = __float2bfloat16(v);
          }
        }
      }
    }
  }
}

// ---------------- MFMA flash attention v2: swapped QK^T, 8 waves, q-tile 128 ----------------
// qb: [B,H,S,64] bf16 pre-scaled; kb: [B,H,S,64]; vt: [B,H,64,S]
__global__ __launch_bounds__(512)
void attn_mfma_kernel(const u16* __restrict__ qb, const u16* __restrict__ kb,
                      const u16* __restrict__ vt, const int* __restrict__ mask,
                      __hip_bfloat16* __restrict__ out){
  __shared__ u16 Ks[64*72];
  __shared__ u16 Vs[64*72];
  __shared__ u16 Pl[8][16*72];
  const int t = threadIdx.x;
  const int wid = t>>6, lane = t&63;
  const int lr = lane&15, lg = lane>>4, lk = lg*8;
  const int bh = blockIdx.y;
  const int b = bh>>4, h = bh&15;
  const int q0 = blockIdx.x*128 + wid*16;
  const u16* qbase = qb + (size_t)bh*1024*64;
  const u16* kbase = kb + (size_t)bh*1024*64;
  const u16* vbase = vt + (size_t)bh*64*1024;
  const int* mrow = mask + b*SEQ;

  // Q fragment: q = q0+lr (B-operand of swapped QK^T); d-chunk dg, elems lg*8..lg*8+7
  bf16x8 aq[2];
  aq[0] = *(const bf16x8*)(qbase + (size_t)(q0+lr)*64 + lk);
  aq[1] = *(const bf16x8*)(qbase + (size_t)(q0+lr)*64 + 32 + lk);

  f32x4 osum[4] = {};
  float m1 = -1e30f, l1 = 0.f;   // running max/denom for q = q0 + lr

  for (int kt=0; kt<SEQ/64; ++kt){
    const int k0 = kt*64;
    __syncthreads();
    {
      // 512 threads: 64 rows x 128B, one b128 per thread per array
      int r = t>>3, sg = (t&7)*8;
      *(u32x4*)&Ks[r*72+sg] = *(const u32x4*)(kbase + (size_t)(k0+r)*64 + sg);
      *(u32x4*)&Vs[r*72+sg] = *(const u32x4*)(vbase + (size_t)r*1024 + k0 + sg);
    }
    __syncthreads();

    unsigned long long bm = __ballot(mrow[k0 + lane] != 0);

    // S^T = K·Q^T: D[key][q], q = lr, key = k4*16 + lg*4 + e
    f32x4 sacc[4] = {};
    __builtin_amdgcn_s_setprio(1);
    #pragma unroll
    for (int k4=0;k4<4;++k4){
      #pragma unroll
      for (int dg=0;dg<2;++dg){
        bf16x8 kf = *(const bf16x8*)&Ks[(k4*16+lr)*72 + dg*32 + lk];
        sacc[k4] = __builtin_amdgcn_mfma_f32_16x16x32_bf16(kf, aq[dg], sacc[k4],0,0,0);
      }
    }
    __builtin_amdgcn_s_setprio(0);
    // mask via ballot bits
    #pragma unroll
    for (int k4=0;k4<4;++k4)
      #pragma unroll
      for (int e=0;e<4;++e)
        if (!((bm >> (k4*16 + lg*4 + e)) & 1)) sacc[k4][e] = -1e30f;

    // softmax for q=lr: 16 in-lane values, then xor-16/32 across lg groups
    float tm = -1e30f;
    #pragma unroll
    for (int k4=0;k4<4;++k4)
      #pragma unroll
      for (int e=0;e<4;++e) tm = fmaxf(tm, sacc[k4][e]);
    tm = fmaxf(tm, __shfl_xor(tm,16));
    tm = fmaxf(tm, __shfl_xor(tm,32));
    float mn = fmaxf(m1, tm);
    float c  = __expf(m1 - mn);
    m1 = mn;
    float ps = 0.f;
    #pragma unroll
    for (int k4=0;k4<4;++k4)
      #pragma unroll
      for (int e=0;e<4;++e){ float p = __expf(sacc[k4][e]-mn); sacc[k4][e]=p; ps+=p; }
    ps += __shfl_xor(ps,16);
    ps += __shfl_xor(ps,32);
    l1 = l1*c + ps;

    // rescale osum rows (row q = lg*4+e) with c fetched from lane lg*4+e
    float ce[4];
    #pragma unroll
    for (int e=0;e<4;++e) ce[e] = __shfl(c, lg*4+e);
    #pragma unroll
    for (int dt=0;dt<4;++dt)
      #pragma unroll
      for (int e=0;e<4;++e) osum[dt][e] *= ce[e];

    // P write: row q=lr, 4 consecutive keys per b64 (keys k4*16+lg*4..+3)
    #pragma unroll
    for (int k4=0;k4<4;++k4){
      u32 lo = (u32)f2bf(sacc[k4][0]) | ((u32)f2bf(sacc[k4][1])<<16);
      u32 hi = (u32)f2bf(sacc[k4][2]) | ((u32)f2bf(sacc[k4][3])<<16);
      u32x2 pk; pk[0]=lo; pk[1]=hi;
      *(u32x2*)&Pl[wid][lr*72 + k4*16 + lg*4] = pk;
    }
    // PV: O[q][d], per-wave Pl (no barrier needed; compiler orders ds ops by dependency)
    __builtin_amdgcn_s_setprio(1);
    #pragma unroll
    for (int dt=0;dt<4;++dt){
      #pragma unroll
      for (int kg=0;kg<2;++kg){
        bf16x8 pa = *(const bf16x8*)&Pl[wid][lr*72 + kg*32 + lk];
        bf16x8 vf = *(const bf16x8*)&Vs[(dt*16+lr)*72 + kg*32 + lk];
        osum[dt] = __builtin_amdgcn_mfma_f32_16x16x32_bf16(pa, vf, osum[dt],0,0,0);
      }
    }
    __builtin_amdgcn_s_setprio(0);
  }
  // epilogue: row q = lg*4+e needs 1/l from lane lg*4+e
  float li[4];
  #pragma unroll
  for (int e=0;e<4;++e) li[e] = 1.f / __shfl(l1, lg*4+e);
  #pragma unroll
  for (int dt=0;dt<4;++dt){
    int d = dt*16 + lr;
    #pragma unroll
    for (int e=0;e<4;++e){
      int q = q0 + lg*4 + e;
      out[((size_t)b*1024 + q)*1024 + h*64 + d] = __float2bfloat16(osum[dt][e] * li[e]);
    }
  }
}

// ---------------- fused: t = relu(a)+res; layernorm(t)*g+b ----------------
__global__ __launch_bounds__(256)
void ln_fused_kernel(const float* __restrict__ a, const float* __restrict__ res,
                     const float* __restrict__ g, const float* __restrict__ be,
                     float* __restrict__ outf, __hip_bfloat16* __restrict__ outb){
  int row = blockIdx.x, t = threadIdx.x;
  size_t rb = (size_t)row*D_MODEL;
  float4 av = *(const float4*)(a  + rb + t*4);
  float4 rv = *(const float4*)(res+ rb + t*4);
  float v0 = fmaxf(av.x,0.f)+rv.x;
  float v1 = fmaxf(av.y,0.f)+rv.y;
  float v2 = fmaxf(av.z,0.f)+rv.z;
  float v3 = fmaxf(av.w,0.f)+rv.w;
  float sum = v0+v1+v2+v3;
  float ss  = v0*v0+v1*v1+v2*v2+v3*v3;
  #pragma unroll
  for (int off=32; off; off>>=1){ sum += __shfl_xor(sum,off); ss += __shfl_xor(ss,off); }
  __shared__ float red[8];
  int wid = t>>6, lane = t&63;
  if (lane==0){ red[wid]=sum; red[4+wid]=ss; }
  __syncthreads();
  sum = red[0]+red[1]+red[2]+red[3];
  ss  = red[4]+red[5]+red[6]+red[7];
  float mu  = sum*(1.f/1024.f);
  float var = ss*(1.f/1024.f) - mu*mu;
  float rstd = rsqrtf(var + 1e-6f);
  float4 gv = *(const float4*)(g  + t*4);
  float4 bv = *(const float4*)(be + t*4);
  float y0=(v0-mu)*rstd*gv.x+bv.x;
  float y1=(v1-mu)*rstd*gv.y+bv.y;
  float y2=(v2-mu)*rstd*gv.z+bv.z;
  float y3=(v3-mu)*rstd*gv.w+bv.w;
  *(float4*)(outf+rb+t*4) = make_float4(y0,y1,y2,y3);
  if (outb){
    outb[rb+t*4+0]=__float2bfloat16(y0);
    outb[rb+t*4+1]=__float2bfloat16(y1);
    outb[rb+t*4+2]=__float2bfloat16(y2);
    outb[rb+t*4+3]=__float2bfloat16(y3);
  }
}

extern "C" void kernel_launch(void* const* d_in, const int* in_sizes, int n_in,
                              void* d_out, int out_size, void* d_ws, size_t ws_size,
                              hipStream_t stream){
  const float* x    = (const float*)d_in[0];
  const int*   mask = (const int*)  d_in[1];
  const float* Wq   = (const float*)d_in[2];
  const float* Wk   = (const float*)d_in[3];
  const float* Wv   = (const float*)d_in[4];
  const float* Wo   = (const float*)d_in[5];
  const float* bo   = (const float*)d_in[6];
  const float* ln1g = (const float*)d_in[7];
  const float* ln1b = (const float*)d_in[8];
  const float* W1   = (const float*)d_in[9];
  const float* b1   = (const float*)d_in[10];
  const float* W2   = (const float*)d_in[11];
  const float* b2   = (const float*)d_in[12];
  const float* ln2g = (const float*)d_in[13];
  const float* ln2b = (const float*)d_in[14];

  char* ws = (char*)d_ws;
  const size_t MB = 1024*1024;
  // WqT/WkT/WvT contiguous -> one [3072][1024] BT for the fused QKV GEMM
  __hip_bfloat16* WqT  = (__hip_bfloat16*)(ws + 0);        // 2MB
  __hip_bfloat16* WkT  = (__hip_bfloat16*)(ws + 2*MB);     // 2MB
  __hip_bfloat16* WvT  = (__hip_bfloat16*)(ws + 4*MB);     // 2MB
  __hip_bfloat16* WoT  = (__hip_bfloat16*)(ws + 6*MB);     // 2MB
  __hip_bfloat16* W1T  = (__hip_bfloat16*)(ws + 8*MB);     // 4MB
  __hip_bfloat16* W2T  = (__hip_bfloat16*)(ws + 12*MB);    // 4MB
  __hip_bfloat16* xb   = (__hip_bfloat16*)(ws + 16*MB);    // 8MB  [dead after QKV]
  float* q_proj        = (float*)(ws + 24*MB);             // 16MB [dead after ln1]
  __hip_bfloat16* qb   = (__hip_bfloat16*)(ws + 40*MB);    // 8MB; kb at +8MB, vt at +16MB
  __hip_bfloat16* attn_o = (__hip_bfloat16*)(ws + 64*MB);  // 8MB  [dead after o-proj]
  float* proj_o        = (float*)(ws + 40*MB);             // reuse qb+kb  [dead after ln1]
  float* h1f           = (float*)(ws + 56*MB);             // reuse vt+attn_o [live till ln2]
  __hip_bfloat16* h1b  = (__hip_bfloat16*)(ws + 16*MB);    // reuse xb
  __hip_bfloat16* ff1b = (__hip_bfloat16*)(ws + 24*MB);    // reuse q_proj (16MB)
  float* ff2           = (float*)(ws + 40*MB);             // reuse proj_o (16MB)

  const float qscale = 0.03125f; // 1/sqrt(D_MODEL)

  // 1. prep
  cast_bf16_kernel<<<ROWS*D_MODEL/4/256, 256, 0, stream>>>(x, xb, ROWS*D_MODEL);
  transpose_cast_kernel<<<dim3(32,32), 256, 0, stream>>>(Wq, WqT, 1024, 1024);
  transpose_cast_kernel<<<dim3(32,32), 256, 0, stream>>>(Wk, WkT, 1024, 1024);
  transpose_cast_kernel<<<dim3(32,32), 256, 0, stream>>>(Wv, WvT, 1024, 1024);
  transpose_cast_kernel<<<dim3(32,32), 256, 0, stream>>>(Wo, WoT, 1024, 1024);
  transpose_cast_kernel<<<dim3(64,32), 256, 0, stream>>>(W1, W1T, 1024, 2048);
  transpose_cast_kernel<<<dim3(32,64), 256, 0, stream>>>(W2, W2T, 2048, 1024);

  // 2. fused QKV projection: N=3072, epilogue routes q/k/v
  gemm_bt_kernel<5><<<dim3(24,32), 256, 0, stream>>>((const u16*)xb, (const u16*)WqT, nullptr,
                                                     q_proj, qb, ROWS, 3072, 1024, qscale);

  // 3. MFMA flash attention (v2: 8 waves, q-tile 128)
  attn_mfma_kernel<<<dim3(SEQ/128, BATCH*N_HEADS), 512, 0, stream>>>(
      (const u16*)qb, (const u16*)(qb + 4194304u), (const u16*)(qb + 8388608u), mask, attn_o);

  // 4. output projection (+bo)
  gemm_bt_kernel<0><<<dim3(8,32), 256, 0, stream>>>((const u16*)attn_o, (const u16*)WoT, bo,
                                                    proj_o, nullptr, ROWS, 1024, 1024, 1.f);

  // 5. ln1: h1 = LN(relu(proj_o) + q_proj)
  ln_fused_kernel<<<ROWS, 256, 0, stream>>>(proj_o, q_proj, ln1g, ln1b, h1f, h1b);

  // 6. FFN1 (+b1, bf16 out)
  gemm_bt_kernel<1><<<dim3(16,32), 256, 0, stream>>>((const u16*)h1b, (const u16*)W1T, b1,
                                                     nullptr, ff1b, ROWS, 2048, 1024, 1.f);

  // 7. FFN2 (+b2, f32 out)
  gemm_bt_kernel<0><<<dim3(8,32), 256, 0, stream>>>((const u16*)ff1b, (const u16*)W2T, b2,
                                                    ff2, nullptr, ROWS, 1024, 2048, 1.f);

  // 8. ln2: y = LN(relu(ff2) + h1)
  ln_fused_kernel<<<ROWS, 256, 0, stream>>>(ff2, h1f, ln2g, ln2b, (float*)d_out, nullptr);
}

// Round 6
// 215.651 us; speedup vs baseline: 20.2777x; 1.0572x over previous
//
#include <hip/hip_runtime.h>
#include <hip/hip_bf16.h>

#define D_MODEL 1024
#define N_HEADS 16
#define D_HEAD  64
#define D_FF    2048
#define BATCH   4
#define SEQ     1024
#define ROWS    (BATCH*SEQ)   // 4096

typedef __bf16  bf16x8 __attribute__((ext_vector_type(8)));
typedef float   f32x4  __attribute__((ext_vector_type(4)));
typedef unsigned int u32x4 __attribute__((ext_vector_type(4)));
typedef unsigned int u32x2 __attribute__((ext_vector_type(2)));
typedef unsigned short u16;
typedef unsigned int u32;

__device__ inline u16 f2bf(float x){ __hip_bfloat16 b = __float2bfloat16(x); return *(u16*)&b; }

// async global->LDS, 16B per lane. gsrc per-lane, ldst wave-uniform base (+lane*16 implicit).
__device__ inline void load_lds16(const u16* gsrc, u16* ldst){
  __builtin_amdgcn_global_load_lds((const __attribute__((address_space(1))) void*)gsrc,
                                   (__attribute__((address_space(3))) void*)ldst, 16, 0, 0);
}

// ---------------- prep: f32 -> bf16 cast ----------------
__global__ __launch_bounds__(256)
void cast_bf16_kernel(const float* __restrict__ src, __hip_bfloat16* __restrict__ dst, int n){
  int i = (blockIdx.x*blockDim.x + threadIdx.x)*4;
  if (i + 3 < n){
    float4 v = *(const float4*)(src + i);
    dst[i+0] = __float2bfloat16(v.x);
    dst[i+1] = __float2bfloat16(v.y);
    dst[i+2] = __float2bfloat16(v.z);
    dst[i+3] = __float2bfloat16(v.w);
  }
}

// ---------------- prep: transpose + cast (W[R][C] -> WT[C][R] bf16) ----------------
__global__ __launch_bounds__(256)
void transpose_cast_kernel(const float* __restrict__ src, __hip_bfloat16* __restrict__ dst,
                           int R, int C){
  __shared__ float tile[32][33];
  int c0 = blockIdx.x*32, r0 = blockIdx.y*32;
  int tx = threadIdx.x & 31, ty = threadIdx.x >> 5;
  #pragma unroll
  for (int i=0;i<32;i+=8)
    tile[ty+i][tx] = src[(size_t)(r0+ty+i)*C + (c0+tx)];
  __syncthreads();
  #pragma unroll
  for (int i=0;i<32;i+=8)
    dst[(size_t)(c0+ty+i)*R + (r0+tx)] = __float2bfloat16(tile[tx][ty+i]);
}

// 4 square 1024x1024 weights in one launch (z selects source; dst contiguous at z*1Mi)
__global__ __launch_bounds__(256)
void transpose4_kernel(const float* __restrict__ s0, const float* __restrict__ s1,
                       const float* __restrict__ s2, const float* __restrict__ s3,
                       __hip_bfloat16* __restrict__ dst){
  __shared__ float tile[32][33];
  const float* src = (blockIdx.z==0)?s0:(blockIdx.z==1)?s1:(blockIdx.z==2)?s2:s3;
  __hip_bfloat16* d = dst + (size_t)blockIdx.z*1024*1024;
  int c0 = blockIdx.x*32, r0 = blockIdx.y*32;
  int tx = threadIdx.x & 31, ty = threadIdx.x >> 5;
  #pragma unroll
  for (int i=0;i<32;i+=8)
    tile[ty+i][tx] = src[(size_t)(r0+ty+i)*1024 + (c0+tx)];
  __syncthreads();
  #pragma unroll
  for (int i=0;i<32;i+=8)
    d[(size_t)(c0+ty+i)*1024 + (r0+tx)] = __float2bfloat16(tile[tx][ty+i]);
}

// ---------------- bf16 MFMA GEMM (m97 structure, BK=64 as 2 conflict-free BK=32 subtiles)
// C[M][N] = A[M][K] @ BT[N][K]^T. 128x128 tile, 4 waves (2x2), linear LDS, global_load_lds w=16.
// MODE: 0=f32 flat, 1=bf16 flat,
//       5=QKV fused: col<1024 -> q_proj f32 + scaled qb head-major; 1024..2047 -> kb head-major;
//                    2048..3071 -> vt d-major [B,H,64,S]. Cb points at qb (kb=+4Mi, vt=+8Mi elems).
template<int MODE>
__global__ __launch_bounds__(256, 2)
void gemm_bt_kernel(const u16* __restrict__ A, const u16* __restrict__ BT,
                    const float* __restrict__ bias, float* __restrict__ Cf,
                    __hip_bfloat16* __restrict__ Cb, int M, int N, int K, float cscale){
  __shared__ u16 As[2][128*32];   // 2 K-halves, 64B rows (conflict-free b128 reads)
  __shared__ u16 Bs[2][128*32];
  const int m0 = blockIdx.y*128, n0 = blockIdx.x*128;
  const int t = threadIdx.x;
  const int wid = t>>6, lane = t&63;
  const int wm = wid>>1, wn = wid&1;
  const int lr = lane&15, lk = (lane>>4)*8;
  const int srow = t>>2, sseg = (t&3)*8;
  const int wbase = wid*512;

  f32x4 acc[4][4] = {};

  for (int kt=0; kt<K; kt+=64){
    __syncthreads();
    #pragma unroll
    for (int half=0; half<2; ++half){
      #pragma unroll
      for (int c=0;c<2;++c){
        load_lds16(A  + (size_t)(m0 + c*64 + srow)*K + kt + half*32 + sseg, &As[half][c*2048 + wbase]);
        load_lds16(BT + (size_t)(n0 + c*64 + srow)*K + kt + half*32 + sseg, &Bs[half][c*2048 + wbase]);
      }
    }
    __syncthreads();
    #pragma unroll
    for (int half=0; half<2; ++half){
      bf16x8 af[4], bfr[4];
      #pragma unroll
      for (int f=0; f<4; ++f){
        af[f]  = *(const bf16x8*)&As[half][(wm*64 + f*16 + lr)*32 + lk];
        bfr[f] = *(const bf16x8*)&Bs[half][(wn*64 + f*16 + lr)*32 + lk];
      }
      #pragma unroll
      for (int i=0;i<4;++i)
        #pragma unroll
        for (int j=0;j<4;++j)
          acc[i][j] = __builtin_amdgcn_mfma_f32_16x16x32_bf16(af[i], bfr[j], acc[i][j], 0,0,0);
    }
  }

  const int r_in = (lane>>4)*4;
  #pragma unroll
  for (int i=0;i<4;++i){
    #pragma unroll
    for (int j=0;j<4;++j){
      int col = n0 + wn*64 + j*16 + lr;
      float bv = bias ? bias[col] : 0.f;
      #pragma unroll
      for (int e=0;e<4;++e){
        int row = m0 + wm*64 + i*16 + r_in + e;
        float v = acc[i][j][e] + bv;
        if (MODE == 0){
          Cf[(size_t)row*N + col] = v;
        } else if (MODE == 1){
          Cb[(size_t)row*N + col] = __float2bfloat16(v);
        } else { // MODE 5: QKV fused epilogue (which is block-uniform)
          int b = row>>10, s = row&1023;
          int which = col>>10, c = col&1023, h = c>>6, d = c&63;
          size_t hm = (((size_t)b*16 + h)*1024 + s)*64 + d;
          if (which == 0){
            Cf[(size_t)row*1024 + c] = v;
            Cb[hm] = __float2bfloat16(v * cscale);
          } else if (which == 1){
            Cb[4194304u + hm] = __float2bfloat16(v);
          } else {
            Cb[8388608u + (((size_t)b*16 + h)*64 + d)*1024 + s] = __float2bfloat16(v);
          }
        }
      }
    }
  }
}

// ---------------- MFMA flash attention v3: swapped QK^T, exp2 domain, defer-max ----------------
// qb: [B,H,S,64] bf16 pre-scaled by log2(e)/sqrt(D_MODEL); kb: [B,H,S,64]; vt: [B,H,64,S]
__global__ __launch_bounds__(512)
void attn_mfma_kernel(const u16* __restrict__ qb, const u16* __restrict__ kb,
                      const u16* __restrict__ vt, const int* __restrict__ mask,
                      __hip_bfloat16* __restrict__ out){
  __shared__ u16 Ks[64*72];
  __shared__ u16 Vs[64*72];
  __shared__ u16 Pl[8][16*72];
  const int t = threadIdx.x;
  const int wid = t>>6, lane = t&63;
  const int lr = lane&15, lg = lane>>4, lk = lg*8;
  const int bh = blockIdx.y;
  const int b = bh>>4, h = bh&15;
  const int q0 = blockIdx.x*128 + wid*16;
  const u16* qbase = qb + (size_t)bh*1024*64;
  const u16* kbase = kb + (size_t)bh*1024*64;
  const u16* vbase = vt + (size_t)bh*64*1024;
  const int* mrow = mask + b*SEQ;

  bf16x8 aq[2];
  aq[0] = *(const bf16x8*)(qbase + (size_t)(q0+lr)*64 + lk);
  aq[1] = *(const bf16x8*)(qbase + (size_t)(q0+lr)*64 + 32 + lk);

  f32x4 osum[4] = {};
  float m1 = -1e30f, l1 = 0.f;   // running ref-max (log2 domain) / denom for q = q0 + lr

  for (int kt=0; kt<SEQ/64; ++kt){
    const int k0 = kt*64;
    __syncthreads();
    {
      int r = t>>3, sg = (t&7)*8;
      *(u32x4*)&Ks[r*72+sg] = *(const u32x4*)(kbase + (size_t)(k0+r)*64 + sg);
      *(u32x4*)&Vs[r*72+sg] = *(const u32x4*)(vbase + (size_t)r*1024 + k0 + sg);
    }
    __syncthreads();

    unsigned long long bm = __ballot(mrow[k0 + lane] != 0);

    // S^T = K·Q^T (log2 domain): D[key][q], q = lr, key = k4*16 + lg*4 + e
    f32x4 sacc[4] = {};
    __builtin_amdgcn_s_setprio(1);
    #pragma unroll
    for (int k4=0;k4<4;++k4){
      #pragma unroll
      for (int dg=0;dg<2;++dg){
        bf16x8 kf = *(const bf16x8*)&Ks[(k4*16+lr)*72 + dg*32 + lk];
        sacc[k4] = __builtin_amdgcn_mfma_f32_16x16x32_bf16(kf, aq[dg], sacc[k4],0,0,0);
      }
    }
    __builtin_amdgcn_s_setprio(0);
    if (bm != ~0ull){  // wave-uniform fast path: skip masking when all keys valid
      #pragma unroll
      for (int k4=0;k4<4;++k4)
        #pragma unroll
        for (int e=0;e<4;++e)
          if (!((bm >> (k4*16 + lg*4 + e)) & 1)) sacc[k4][e] = -1e30f;
    }

    // tile max for q=lr: 16 in-lane, then xor-16/32 across lg groups
    float tm = -1e30f;
    #pragma unroll
    for (int k4=0;k4<4;++k4)
      #pragma unroll
      for (int e=0;e<4;++e) tm = fmaxf(tm, sacc[k4][e]);
    tm = fmaxf(tm, __shfl_xor(tm,16));
    tm = fmaxf(tm, __shfl_xor(tm,32));

    // defer-max (T13): skip rescale while tile max stays within 2^8 of ref
    float mn = m1, c = 1.f;
    bool need = !__all(tm <= m1 + 8.f);
    if (need){
      mn = fmaxf(m1, tm);
      c  = exp2f(m1 - mn);
      m1 = mn;
    }
    float ps = 0.f;
    #pragma unroll
    for (int k4=0;k4<4;++k4)
      #pragma unroll
      for (int e=0;e<4;++e){ float p = exp2f(sacc[k4][e]-mn); sacc[k4][e]=p; ps+=p; }
    ps += __shfl_xor(ps,16);
    ps += __shfl_xor(ps,32);
    l1 = l1*c + ps;

    if (need){
      float ce[4];
      #pragma unroll
      for (int e=0;e<4;++e) ce[e] = __shfl(c, lg*4+e);
      #pragma unroll
      for (int dt=0;dt<4;++dt)
        #pragma unroll
        for (int e=0;e<4;++e) osum[dt][e] *= ce[e];
    }

    // P write: row q=lr, 4 consecutive keys per b64 (keys k4*16+lg*4..+3)
    #pragma unroll
    for (int k4=0;k4<4;++k4){
      u32 lo = (u32)f2bf(sacc[k4][0]) | ((u32)f2bf(sacc[k4][1])<<16);
      u32 hi = (u32)f2bf(sacc[k4][2]) | ((u32)f2bf(sacc[k4][3])<<16);
      u32x2 pk; pk[0]=lo; pk[1]=hi;
      *(u32x2*)&Pl[wid][lr*72 + k4*16 + lg*4] = pk;
    }
    // PV: O[q][d] (per-wave Pl; compiler orders ds ops by dependency)
    __builtin_amdgcn_s_setprio(1);
    #pragma unroll
    for (int dt=0;dt<4;++dt){
      #pragma unroll
      for (int kg=0;kg<2;++kg){
        bf16x8 pa = *(const bf16x8*)&Pl[wid][lr*72 + kg*32 + lk];
        bf16x8 vf = *(const bf16x8*)&Vs[(dt*16+lr)*72 + kg*32 + lk];
        osum[dt] = __builtin_amdgcn_mfma_f32_16x16x32_bf16(pa, vf, osum[dt],0,0,0);
      }
    }
    __builtin_amdgcn_s_setprio(0);
  }
  // epilogue: row q = lg*4+e needs 1/l from lane lg*4+e
  float li[4];
  #pragma unroll
  for (int e=0;e<4;++e) li[e] = 1.f / __shfl(l1, lg*4+e);
  #pragma unroll
  for (int dt=0;dt<4;++dt){
    int d = dt*16 + lr;
    #pragma unroll
    for (int e=0;e<4;++e){
      int q = q0 + lg*4 + e;
      out[((size_t)b*1024 + q)*1024 + h*64 + d] = __float2bfloat16(osum[dt][e] * li[e]);
    }
  }
}

// ---------------- fused: t = relu(a)+res; layernorm(t)*g+b ----------------
__global__ __launch_bounds__(256)
void ln_fused_kernel(const float* __restrict__ a, const float* __restrict__ res,
                     const float* __restrict__ g, const float* __restrict__ be,
                     float* __restrict__ outf, __hip_bfloat16* __restrict__ outb){
  int row = blockIdx.x, t = threadIdx.x;
  size_t rb = (size_t)row*D_MODEL;
  float4 av = *(const float4*)(a  + rb + t*4);
  float4 rv = *(const float4*)(res+ rb + t*4);
  float v0 = fmaxf(av.x,0.f)+rv.x;
  float v1 = fmaxf(av.y,0.f)+rv.y;
  float v2 = fmaxf(av.z,0.f)+rv.z;
  float v3 = fmaxf(av.w,0.f)+rv.w;
  float sum = v0+v1+v2+v3;
  float ss  = v0*v0+v1*v1+v2*v2+v3*v3;
  #pragma unroll
  for (int off=32; off; off>>=1){ sum += __shfl_xor(sum,off); ss += __shfl_xor(ss,off); }
  __shared__ float red[8];
  int wid = t>>6, lane = t&63;
  if (lane==0){ red[wid]=sum; red[4+wid]=ss; }
  __syncthreads();
  sum = red[0]+red[1]+red[2]+red[3];
  ss  = red[4]+red[5]+red[6]+red[7];
  float mu  = sum*(1.f/1024.f);
  float var = ss*(1.f/1024.f) - mu*mu;
  float rstd = rsqrtf(var + 1e-6f);
  float4 gv = *(const float4*)(g  + t*4);
  float4 bv = *(const float4*)(be + t*4);
  float y0=(v0-mu)*rstd*gv.x+bv.x;
  float y1=(v1-mu)*rstd*gv.y+bv.y;
  float y2=(v2-mu)*rstd*gv.z+bv.z;
  float y3=(v3-mu)*rstd*gv.w+bv.w;
  *(float4*)(outf+rb+t*4) = make_float4(y0,y1,y2,y3);
  if (outb){
    outb[rb+t*4+0]=__float2bfloat16(y0);
    outb[rb+t*4+1]=__float2bfloat16(y1);
    outb[rb+t*4+2]=__float2bfloat16(y2);
    outb[rb+t*4+3]=__float2bfloat16(y3);
  }
}

extern "C" void kernel_launch(void* const* d_in, const int* in_sizes, int n_in,
                              void* d_out, int out_size, void* d_ws, size_t ws_size,
                              hipStream_t stream){
  const float* x    = (const float*)d_in[0];
  const int*   mask = (const int*)  d_in[1];
  const float* Wq   = (const float*)d_in[2];
  const float* Wk   = (const float*)d_in[3];
  const float* Wv   = (const float*)d_in[4];
  const float* Wo   = (const float*)d_in[5];
  const float* bo   = (const float*)d_in[6];
  const float* ln1g = (const float*)d_in[7];
  const float* ln1b = (const float*)d_in[8];
  const float* W1   = (const float*)d_in[9];
  const float* b1   = (const float*)d_in[10];
  const float* W2   = (const float*)d_in[11];
  const float* b2   = (const float*)d_in[12];
  const float* ln2g = (const float*)d_in[13];
  const float* ln2b = (const float*)d_in[14];

  char* ws = (char*)d_ws;
  const size_t MB = 1024*1024;
  // WqT/WkT/WvT contiguous -> one [3072][1024] BT for the fused QKV GEMM
  __hip_bfloat16* WqT  = (__hip_bfloat16*)(ws + 0);        // 2MB (x4 squares contiguous)
  __hip_bfloat16* WoT  = (__hip_bfloat16*)(ws + 6*MB);     // 2MB
  __hip_bfloat16* W1T  = (__hip_bfloat16*)(ws + 8*MB);     // 4MB
  __hip_bfloat16* W2T  = (__hip_bfloat16*)(ws + 12*MB);    // 4MB
  __hip_bfloat16* xb   = (__hip_bfloat16*)(ws + 16*MB);    // 8MB  [dead after QKV]
  float* q_proj        = (float*)(ws + 24*MB);             // 16MB [dead after ln1]
  __hip_bfloat16* qb   = (__hip_bfloat16*)(ws + 40*MB);    // 8MB; kb at +8MB, vt at +16MB
  __hip_bfloat16* attn_o = (__hip_bfloat16*)(ws + 64*MB);  // 8MB  [dead after o-proj]
  float* proj_o        = (float*)(ws + 40*MB);             // reuse qb+kb  [dead after ln1]
  float* h1f           = (float*)(ws + 56*MB);             // reuse vt+attn_o [live till ln2]
  __hip_bfloat16* h1b  = (__hip_bfloat16*)(ws + 16*MB);    // reuse xb
  __hip_bfloat16* ff1b = (__hip_bfloat16*)(ws + 24*MB);    // reuse q_proj (16MB)
  float* ff2           = (float*)(ws + 40*MB);             // reuse proj_o (16MB)

  const float qscale = 0.03125f * 1.44269504f; // log2(e)/sqrt(D_MODEL)

  // 1. prep
  cast_bf16_kernel<<<ROWS*D_MODEL/4/256, 256, 0, stream>>>(x, xb, ROWS*D_MODEL);
  transpose4_kernel<<<dim3(32,32,4), 256, 0, stream>>>(Wq, Wk, Wv, Wo, WqT);
  transpose_cast_kernel<<<dim3(64,32), 256, 0, stream>>>(W1, W1T, 1024, 2048);
  transpose_cast_kernel<<<dim3(32,64), 256, 0, stream>>>(W2, W2T, 2048, 1024);

  // 2. fused QKV projection: N=3072, epilogue routes q/k/v
  gemm_bt_kernel<5><<<dim3(24,32), 256, 0, stream>>>((const u16*)xb, (const u16*)WqT, nullptr,
                                                     q_proj, qb, ROWS, 3072, 1024, qscale);

  // 3. MFMA flash attention
  attn_mfma_kernel<<<dim3(SEQ/128, BATCH*N_HEADS), 512, 0, stream>>>(
      (const u16*)qb, (const u16*)(qb + 4194304u), (const u16*)(qb + 8388608u), mask, attn_o);

  // 4. output projection (+bo)
  gemm_bt_kernel<0><<<dim3(8,32), 256, 0, stream>>>((const u16*)attn_o, (const u16*)WoT, bo,
                                                    proj_o, nullptr, ROWS, 1024, 1024, 1.f);

  // 5. ln1: h1 = LN(relu(proj_o) + q_proj)
  ln_fused_kernel<<<ROWS, 256, 0, stream>>>(proj_o, q_proj, ln1g, ln1b, h1f, h1b);

  // 6. FFN1 (+b1, bf16 out)
  gemm_bt_kernel<1><<<dim3(16,32), 256, 0, stream>>>((const u16*)h1b, (const u16*)W1T, b1,
                                                     nullptr, ff1b, ROWS, 2048, 1024, 1.f);

  // 7. FFN2 (+b2, f32 out)
  gemm_bt_kernel<0><<<dim3(8,32), 256, 0, stream>>>((const u16*)ff1b, (const u16*)W2T, b2,
                                                    ff2, nullptr, ROWS, 1024, 2048, 1.f);

  // 8. ln2: y = LN(relu(ff2) + h1)
  ln_fused_kernel<<<ROWS, 256, 0, stream>>>(ff2, h1f, ln2g, ln2b, (float*)d_out, nullptr);
}

// Round 7
// 209.125 us; speedup vs baseline: 20.9105x; 1.0312x over previous
//
#include <hip/hip_runtime.h>
#include <hip/hip_bf16.h>

#define D_MODEL 1024
#define N_HEADS 16
#define D_HEAD  64
#define D_FF    2048
#define BATCH   4
#define SEQ     1024
#define ROWS    (BATCH*SEQ)   // 4096

typedef __bf16  bf16x8 __attribute__((ext_vector_type(8)));
typedef float   f32x4  __attribute__((ext_vector_type(4)));
typedef unsigned int u32x4 __attribute__((ext_vector_type(4)));
typedef unsigned int u32x2 __attribute__((ext_vector_type(2)));
typedef unsigned short u16;
typedef unsigned int u32;

__device__ inline u16 f2bf(float x){ __hip_bfloat16 b = __float2bfloat16(x); return *(u16*)&b; }

// async global->LDS, 16B per lane. gsrc per-lane, ldst wave-uniform base (+lane*16 implicit).
__device__ inline void load_lds16(const u16* gsrc, u16* ldst){
  __builtin_amdgcn_global_load_lds((const __attribute__((address_space(1))) void*)gsrc,
                                   (__attribute__((address_space(3))) void*)ldst, 16, 0, 0);
}

// ---------------- prep: f32 -> bf16 cast ----------------
__global__ __launch_bounds__(256)
void cast_bf16_kernel(const float* __restrict__ src, __hip_bfloat16* __restrict__ dst, int n){
  int i = (blockIdx.x*blockDim.x + threadIdx.x)*4;
  if (i + 3 < n){
    float4 v = *(const float4*)(src + i);
    dst[i+0] = __float2bfloat16(v.x);
    dst[i+1] = __float2bfloat16(v.y);
    dst[i+2] = __float2bfloat16(v.z);
    dst[i+3] = __float2bfloat16(v.w);
  }
}

// ---------------- prep: transpose + cast (W[R][C] -> WT[C][R] bf16) ----------------
__global__ __launch_bounds__(256)
void transpose_cast_kernel(const float* __restrict__ src, __hip_bfloat16* __restrict__ dst,
                           int R, int C){
  __shared__ float tile[32][33];
  int c0 = blockIdx.x*32, r0 = blockIdx.y*32;
  int tx = threadIdx.x & 31, ty = threadIdx.x >> 5;
  #pragma unroll
  for (int i=0;i<32;i+=8)
    tile[ty+i][tx] = src[(size_t)(r0+ty+i)*C + (c0+tx)];
  __syncthreads();
  #pragma unroll
  for (int i=0;i<32;i+=8)
    dst[(size_t)(c0+ty+i)*R + (r0+tx)] = __float2bfloat16(tile[tx][ty+i]);
}

// 4 square 1024x1024 weights in one launch (z selects source; dst contiguous at z*1Mi)
__global__ __launch_bounds__(256)
void transpose4_kernel(const float* __restrict__ s0, const float* __restrict__ s1,
                       const float* __restrict__ s2, const float* __restrict__ s3,
                       __hip_bfloat16* __restrict__ dst){
  __shared__ float tile[32][33];
  const float* src = (blockIdx.z==0)?s0:(blockIdx.z==1)?s1:(blockIdx.z==2)?s2:s3;
  __hip_bfloat16* d = dst + (size_t)blockIdx.z*1024*1024;
  int c0 = blockIdx.x*32, r0 = blockIdx.y*32;
  int tx = threadIdx.x & 31, ty = threadIdx.x >> 5;
  #pragma unroll
  for (int i=0;i<32;i+=8)
    tile[ty+i][tx] = src[(size_t)(r0+ty+i)*1024 + (c0+tx)];
  __syncthreads();
  #pragma unroll
  for (int i=0;i<32;i+=8)
    d[(size_t)(c0+ty+i)*1024 + (r0+tx)] = __float2bfloat16(tile[tx][ty+i]);
}

// ---------------- bf16 MFMA GEMM (m97 structure, BK=64 as 2 conflict-free BK=32 subtiles)
// C[M][N] = A[M][K] @ BT[N][K]^T. 128x128 tile, 4 waves (2x2), linear LDS, global_load_lds w=16.
// MODE: 0=f32 flat, 1=bf16 flat, 6=f32 flat t=relu(v+bias)+res[row][col],
//       5=QKV fused: col<1024 -> q_proj f32 + scaled qb head-major; 1024..2047 -> kb head-major;
//                    2048..3071 -> vt d-major [B,H,64,S]. Cb points at qb (kb=+4Mi, vt=+8Mi elems).
template<int MODE>
__global__ __launch_bounds__(256, 2)
void gemm_bt_kernel(const u16* __restrict__ A, const u16* __restrict__ BT,
                    const float* __restrict__ bias, const float* __restrict__ res,
                    float* __restrict__ Cf, __hip_bfloat16* __restrict__ Cb,
                    int M, int N, int K, float cscale){
  __shared__ u16 As[2][128*32];   // 2 K-halves, 64B rows
  __shared__ u16 Bs[2][128*32];
  const int m0 = blockIdx.y*128, n0 = blockIdx.x*128;
  const int t = threadIdx.x;
  const int wid = t>>6, lane = t&63;
  const int wm = wid>>1, wn = wid&1;
  const int lr = lane&15, lk = (lane>>4)*8;
  const int srow = t>>2, sseg = (t&3)*8;
  const int wbase = wid*512;

  f32x4 acc[4][4] = {};

  for (int kt=0; kt<K; kt+=64){
    __syncthreads();
    #pragma unroll
    for (int half=0; half<2; ++half){
      #pragma unroll
      for (int c=0;c<2;++c){
        load_lds16(A  + (size_t)(m0 + c*64 + srow)*K + kt + half*32 + sseg, &As[half][c*2048 + wbase]);
        load_lds16(BT + (size_t)(n0 + c*64 + srow)*K + kt + half*32 + sseg, &Bs[half][c*2048 + wbase]);
      }
    }
    __syncthreads();
    #pragma unroll
    for (int half=0; half<2; ++half){
      bf16x8 af[4], bfr[4];
      #pragma unroll
      for (int f=0; f<4; ++f){
        af[f]  = *(const bf16x8*)&As[half][(wm*64 + f*16 + lr)*32 + lk];
        bfr[f] = *(const bf16x8*)&Bs[half][(wn*64 + f*16 + lr)*32 + lk];
      }
      #pragma unroll
      for (int i=0;i<4;++i)
        #pragma unroll
        for (int j=0;j<4;++j)
          acc[i][j] = __builtin_amdgcn_mfma_f32_16x16x32_bf16(af[i], bfr[j], acc[i][j], 0,0,0);
    }
  }

  const int r_in = (lane>>4)*4;
  #pragma unroll
  for (int i=0;i<4;++i){
    #pragma unroll
    for (int j=0;j<4;++j){
      int col = n0 + wn*64 + j*16 + lr;
      float bv = bias ? bias[col] : 0.f;
      #pragma unroll
      for (int e=0;e<4;++e){
        int row = m0 + wm*64 + i*16 + r_in + e;
        float v = acc[i][j][e] + bv;
        if (MODE == 0){
          Cf[(size_t)row*N + col] = v;
        } else if (MODE == 1){
          Cb[(size_t)row*N + col] = __float2bfloat16(v);
        } else if (MODE == 6){
          Cf[(size_t)row*N + col] = fmaxf(v,0.f) + res[(size_t)row*N + col];
        } else { // MODE 5: QKV fused epilogue (which is block-uniform)
          int b = row>>10, s = row&1023;
          int which = col>>10, c = col&1023, h = c>>6, d = c&63;
          size_t hm = (((size_t)b*16 + h)*1024 + s)*64 + d;
          if (which == 0){
            Cf[(size_t)row*1024 + c] = v;
            Cb[hm] = __float2bfloat16(v * cscale);
          } else if (which == 1){
            Cb[4194304u + hm] = __float2bfloat16(v);
          } else {
            Cb[8388608u + (((size_t)b*16 + h)*64 + d)*1024 + s] = __float2bfloat16(v);
          }
        }
      }
    }
  }
}

// ---------------- MFMA flash attention v4: dbuf LDS, async-stage split, XCD swizzle ----------------
// qb: [B,H,S,64] bf16 pre-scaled by log2(e)/sqrt(D_MODEL); kb: [B,H,S,64]; vt: [B,H,64,S]
// Flat grid 512: xcd = bid&7 gets 8 consecutive bh (all q-tiles of a bh co-XCD for K/V L2 reuse).
__global__ __launch_bounds__(512)
void attn_mfma_kernel(const u16* __restrict__ qb, const u16* __restrict__ kb,
                      const u16* __restrict__ vt, const int* __restrict__ mask,
                      __hip_bfloat16* __restrict__ out){
  __shared__ u16 Ks[2][64*72];
  __shared__ u16 Vs[2][64*72];
  __shared__ u16 Pl[8][16*72];
  const int t = threadIdx.x;
  const int wid = t>>6, lane = t&63;
  const int lr = lane&15, lg = lane>>4, lk = lg*8;
  const int bid = blockIdx.x;
  const int xcd = bid & 7, slot = bid >> 3;   // 64 slots per xcd
  const int bh = xcd*8 + (slot>>3);
  const int qx = slot & 7;
  const int b = bh>>4, h = bh&15;
  const int q0 = qx*128 + wid*16;
  const u16* qbase = qb + (size_t)bh*1024*64;
  const u16* kbase = kb + (size_t)bh*1024*64;
  const u16* vbase = vt + (size_t)bh*64*1024;
  const int* mrow = mask + b*SEQ;

  bf16x8 aq[2];
  aq[0] = *(const bf16x8*)(qbase + (size_t)(q0+lr)*64 + lk);
  aq[1] = *(const bf16x8*)(qbase + (size_t)(q0+lr)*64 + 32 + lk);

  f32x4 osum[4] = {};
  float m1 = -1e30f, l1 = 0.f;   // running ref-max (log2 domain) / denom for q = q0 + lr

  const int sr = t>>3, sg = (t&7)*8;  // staging: 512 thr cover 64 rows x 128B
  // prologue: stage tile 0
  {
    u32x4 kr = *(const u32x4*)(kbase + (size_t)sr*64 + sg);
    u32x4 vr = *(const u32x4*)(vbase + (size_t)sr*1024 + sg);
    *(u32x4*)&Ks[0][sr*72+sg] = kr;
    *(u32x4*)&Vs[0][sr*72+sg] = vr;
  }
  __syncthreads();

  for (int kt=0; kt<SEQ/64; ++kt){
    const int k0 = kt*64;
    const int cur = kt&1;
    // async-stage split: issue next tile's global loads now, write to LDS after compute
    u32x4 kr, vr;
    const bool more = (kt+1 < SEQ/64);
    if (more){
      kr = *(const u32x4*)(kbase + (size_t)(k0+64+sr)*64 + sg);
      vr = *(const u32x4*)(vbase + (size_t)sr*1024 + (k0+64) + sg);
    }

    unsigned long long bm = __ballot(mrow[k0 + lane] != 0);

    // S^T = K·Q^T (log2 domain): D[key][q], q = lr, key = k4*16 + lg*4 + e
    f32x4 sacc[4] = {};
    __builtin_amdgcn_s_setprio(1);
    #pragma unroll
    for (int k4=0;k4<4;++k4){
      #pragma unroll
      for (int dg=0;dg<2;++dg){
        bf16x8 kf = *(const bf16x8*)&Ks[cur][(k4*16+lr)*72 + dg*32 + lk];
        sacc[k4] = __builtin_amdgcn_mfma_f32_16x16x32_bf16(kf, aq[dg], sacc[k4],0,0,0);
      }
    }
    __builtin_amdgcn_s_setprio(0);
    if (bm != ~0ull){
      #pragma unroll
      for (int k4=0;k4<4;++k4)
        #pragma unroll
        for (int e=0;e<4;++e)
          if (!((bm >> (k4*16 + lg*4 + e)) & 1)) sacc[k4][e] = -1e30f;
    }

    float tm = -1e30f;
    #pragma unroll
    for (int k4=0;k4<4;++k4)
      #pragma unroll
      for (int e=0;e<4;++e) tm = fmaxf(tm, sacc[k4][e]);
    tm = fmaxf(tm, __shfl_xor(tm,16));
    tm = fmaxf(tm, __shfl_xor(tm,32));

    // defer-max (T13)
    float mn = m1, c = 1.f;
    bool need = !__all(tm <= m1 + 8.f);
    if (need){
      mn = fmaxf(m1, tm);
      c  = exp2f(m1 - mn);
      m1 = mn;
    }
    float ps = 0.f;
    #pragma unroll
    for (int k4=0;k4<4;++k4)
      #pragma unroll
      for (int e=0;e<4;++e){ float p = exp2f(sacc[k4][e]-mn); sacc[k4][e]=p; ps+=p; }
    ps += __shfl_xor(ps,16);
    ps += __shfl_xor(ps,32);
    l1 = l1*c + ps;

    if (need){
      float ce[4];
      #pragma unroll
      for (int e=0;e<4;++e) ce[e] = __shfl(c, lg*4+e);
      #pragma unroll
      for (int dt=0;dt<4;++dt)
        #pragma unroll
        for (int e=0;e<4;++e) osum[dt][e] *= ce[e];
    }

    // P write: row q=lr, 4 consecutive keys per b64
    #pragma unroll
    for (int k4=0;k4<4;++k4){
      u32 lo = (u32)f2bf(sacc[k4][0]) | ((u32)f2bf(sacc[k4][1])<<16);
      u32 hi = (u32)f2bf(sacc[k4][2]) | ((u32)f2bf(sacc[k4][3])<<16);
      u32x2 pk; pk[0]=lo; pk[1]=hi;
      *(u32x2*)&Pl[wid][lr*72 + k4*16 + lg*4] = pk;
    }
    // PV: O[q][d]
    __builtin_amdgcn_s_setprio(1);
    #pragma unroll
    for (int dt=0;dt<4;++dt){
      #pragma unroll
      for (int kg=0;kg<2;++kg){
        bf16x8 pa = *(const bf16x8*)&Pl[wid][lr*72 + kg*32 + lk];
        bf16x8 vf = *(const bf16x8*)&Vs[cur][(dt*16+lr)*72 + kg*32 + lk];
        osum[dt] = __builtin_amdgcn_mfma_f32_16x16x32_bf16(pa, vf, osum[dt],0,0,0);
      }
    }
    __builtin_amdgcn_s_setprio(0);

    // write next tile into the other buffer (vmcnt wait on kr/vr happens here)
    if (more){
      *(u32x4*)&Ks[cur^1][sr*72+sg] = kr;
      *(u32x4*)&Vs[cur^1][sr*72+sg] = vr;
    }
    __syncthreads();
  }
  // epilogue: row q = lg*4+e needs 1/l from lane lg*4+e
  float li[4];
  #pragma unroll
  for (int e=0;e<4;++e) li[e] = 1.f / __shfl(l1, lg*4+e);
  #pragma unroll
  for (int dt=0;dt<4;++dt){
    int d = dt*16 + lr;
    #pragma unroll
    for (int e=0;e<4;++e){
      int q = q0 + lg*4 + e;
      out[((size_t)b*1024 + q)*1024 + h*64 + d] = __float2bfloat16(osum[dt][e] * li[e]);
    }
  }
}

// ---------------- plain LN: y = layernorm(a)*g+b -> outf (+ optional bf16) ----------------
__global__ __launch_bounds__(256)
void ln_kernel(const float* __restrict__ a, const float* __restrict__ g,
               const float* __restrict__ be, float* __restrict__ outf,
               __hip_bfloat16* __restrict__ outb){
  int row = blockIdx.x, t = threadIdx.x;
  size_t rb = (size_t)row*D_MODEL;
  float4 av = *(const float4*)(a + rb + t*4);
  float v0 = av.x, v1 = av.y, v2 = av.z, v3 = av.w;
  float sum = v0+v1+v2+v3;
  float ss  = v0*v0+v1*v1+v2*v2+v3*v3;
  #pragma unroll
  for (int off=32; off; off>>=1){ sum += __shfl_xor(sum,off); ss += __shfl_xor(ss,off); }
  __shared__ float red[8];
  int wid = t>>6, lane = t&63;
  if (lane==0){ red[wid]=sum; red[4+wid]=ss; }
  __syncthreads();
  sum = red[0]+red[1]+red[2]+red[3];
  ss  = red[4]+red[5]+red[6]+red[7];
  float mu  = sum*(1.f/1024.f);
  float var = ss*(1.f/1024.f) - mu*mu;
  float rstd = rsqrtf(var + 1e-6f);
  float4 gv = *(const float4*)(g  + t*4);
  float4 bv = *(const float4*)(be + t*4);
  float y0=(v0-mu)*rstd*gv.x+bv.x;
  float y1=(v1-mu)*rstd*gv.y+bv.y;
  float y2=(v2-mu)*rstd*gv.z+bv.z;
  float y3=(v3-mu)*rstd*gv.w+bv.w;
  *(float4*)(outf+rb+t*4) = make_float4(y0,y1,y2,y3);
  if (outb){
    outb[rb+t*4+0]=__float2bfloat16(y0);
    outb[rb+t*4+1]=__float2bfloat16(y1);
    outb[rb+t*4+2]=__float2bfloat16(y2);
    outb[rb+t*4+3]=__float2bfloat16(y3);
  }
}

extern "C" void kernel_launch(void* const* d_in, const int* in_sizes, int n_in,
                              void* d_out, int out_size, void* d_ws, size_t ws_size,
                              hipStream_t stream){
  const float* x    = (const float*)d_in[0];
  const int*   mask = (const int*)  d_in[1];
  const float* Wq   = (const float*)d_in[2];
  const float* Wk   = (const float*)d_in[3];
  const float* Wv   = (const float*)d_in[4];
  const float* Wo   = (const float*)d_in[5];
  const float* bo   = (const float*)d_in[6];
  const float* ln1g = (const float*)d_in[7];
  const float* ln1b = (const float*)d_in[8];
  const float* W1   = (const float*)d_in[9];
  const float* b1   = (const float*)d_in[10];
  const float* W2   = (const float*)d_in[11];
  const float* b2   = (const float*)d_in[12];
  const float* ln2g = (const float*)d_in[13];
  const float* ln2b = (const float*)d_in[14];

  char* ws = (char*)d_ws;
  const size_t MB = 1024*1024;
  // WqT/WkT/WvT contiguous -> one [3072][1024] BT for the fused QKV GEMM
  __hip_bfloat16* WqT  = (__hip_bfloat16*)(ws + 0);        // 2MB x4 squares contiguous
  __hip_bfloat16* WoT  = (__hip_bfloat16*)(ws + 6*MB);     // 2MB
  __hip_bfloat16* W1T  = (__hip_bfloat16*)(ws + 8*MB);     // 4MB
  __hip_bfloat16* W2T  = (__hip_bfloat16*)(ws + 12*MB);    // 4MB
  __hip_bfloat16* xb   = (__hip_bfloat16*)(ws + 16*MB);    // 8MB  [dead after QKV]
  float* q_proj        = (float*)(ws + 24*MB);             // 16MB [dead after O-proj epi]
  __hip_bfloat16* qb   = (__hip_bfloat16*)(ws + 40*MB);    // 8MB; kb at +8MB, vt at +16MB
  __hip_bfloat16* attn_o = (__hip_bfloat16*)(ws + 64*MB);  // 8MB  [dead after o-proj]
  float* t1f           = (float*)(ws + 40*MB);             // reuse qb+kb  [dead after ln1]
  float* h1f           = (float*)(ws + 56*MB);             // reuse vt+attn_o [live till ln2]
  __hip_bfloat16* h1b  = (__hip_bfloat16*)(ws + 16*MB);    // reuse xb
  __hip_bfloat16* ff1b = (__hip_bfloat16*)(ws + 24*MB);    // reuse q_proj (16MB)
  float* t2f           = (float*)(ws + 40*MB);             // reuse t1f (16MB)

  const float qscale = 0.03125f * 1.44269504f; // log2(e)/sqrt(D_MODEL)

  // 1. prep
  cast_bf16_kernel<<<ROWS*D_MODEL/4/256, 256, 0, stream>>>(x, xb, ROWS*D_MODEL);
  transpose4_kernel<<<dim3(32,32,4), 256, 0, stream>>>(Wq, Wk, Wv, Wo, WqT);
  transpose_cast_kernel<<<dim3(64,32), 256, 0, stream>>>(W1, W1T, 1024, 2048);
  transpose_cast_kernel<<<dim3(32,64), 256, 0, stream>>>(W2, W2T, 2048, 1024);

  // 2. fused QKV projection: N=3072, epilogue routes q/k/v
  gemm_bt_kernel<5><<<dim3(24,32), 256, 0, stream>>>((const u16*)xb, (const u16*)WqT, nullptr,
                                                     nullptr, q_proj, qb, ROWS, 3072, 1024, qscale);

  // 3. MFMA flash attention (flat grid, XCD-swizzled)
  attn_mfma_kernel<<<512, 512, 0, stream>>>(
      (const u16*)qb, (const u16*)(qb + 4194304u), (const u16*)(qb + 8388608u), mask, attn_o);

  // 4. output projection (+bo) with fused relu+residual: t1 = relu(attn_o@Wo+bo)+q_proj
  gemm_bt_kernel<6><<<dim3(8,32), 256, 0, stream>>>((const u16*)attn_o, (const u16*)WoT, bo,
                                                    q_proj, t1f, nullptr, ROWS, 1024, 1024, 1.f);

  // 5. ln1: h1 = LN(t1)
  ln_kernel<<<ROWS, 256, 0, stream>>>(t1f, ln1g, ln1b, h1f, h1b);

  // 6. FFN1 (+b1, bf16 out)
  gemm_bt_kernel<1><<<dim3(16,32), 256, 0, stream>>>((const u16*)h1b, (const u16*)W1T, b1,
                                                     nullptr, nullptr, ff1b, ROWS, 2048, 1024, 1.f);

  // 7. FFN2 (+b2) with fused relu+residual: t2 = relu(ff1@W2+b2)+h1
  gemm_bt_kernel<6><<<dim3(8,32), 256, 0, stream>>>((const u16*)ff1b, (const u16*)W2T, b2,
                                                    h1f, t2f, nullptr, ROWS, 1024, 2048, 1.f);

  // 8. ln2: y = LN(t2)
  ln_kernel<<<ROWS, 256, 0, stream>>>(t2f, ln2g, ln2b, (float*)d_out, nullptr);
}